// Round 1
// baseline (4779.546 us; speedup 1.0000x reference)
//
#include <hip/hip_runtime.h>
#include <hip/hip_bf16.h>

// RNNDecoder: emb -> 2-layer LSTM (seq over T=128) -> generator + log_softmax
// T=128 B=32 E=512 H=512 G=2048 V=32000
//
// ws layout (bytes):
//  [0)            Wg_bf16   [32000][512]            32,768,000
//  [32768000)     W0e_bf16  [2048][512]              2,097,152
//  [34865152)     Wr0p_bf16 [2048][1024]             4,194,304
//  [39059456)     Wr1p_bf16 [2048][1024]             4,194,304
//  [43253760)     b1p f32   [2048]                       8,192
//  [43261952)     bias0c f32[2048]                       8,192
//  [43270144)     wcd f32   [2048]                       8,192
//  [43278336)     xcat0 bf16[32][1024]                  65,536
//  [43343872)     xcat1 bf16[32][1024]                  65,536
//  [43409408)     emb_bf16  [4096][512]              4,194,304
//  [47603712)     out_bf16  [4096][512]              4,194,304
//  [51798016)     P0t f32   [2048][4096]            33,554,432
//  [85352448)     barrier ctr                            256
// total ~85.4 MB

typedef __attribute__((ext_vector_type(8))) short bf16x8;
typedef __attribute__((ext_vector_type(4))) float f32x4;
typedef __attribute__((ext_vector_type(2))) unsigned long long u64x2;

#define AS1 __attribute__((address_space(1)))
#define AS3 __attribute__((address_space(3)))

__device__ __forceinline__ unsigned short f2bf(float f) {
  unsigned int u = __builtin_bit_cast(unsigned int, f);
  u += 0x7fffu + ((u >> 16) & 1u);            // round-to-nearest-even
  return (unsigned short)(u >> 16);
}

__device__ __forceinline__ void gl16(const void* g, void* l) {
  __builtin_amdgcn_global_load_lds((const AS1 unsigned int*)g,
                                   (AS3 unsigned int*)l, 16, 0, 0);
}

__device__ __forceinline__ float sigm(float x) { return 1.0f / (1.0f + __expf(-x)); }

// ---------------------------------------------------------------------------
// prep: dtype conversion + weight re-layout + initial xcat0
// Wr0p[gp][k], gp = 4*j + gate (gate-interleaved), g = gate*512 + j
//   k<512 : Whh0[g][k]      (h_prev part)
//   k>=512: Wih0[g][513+k-512]  (out_prev part; col 512 of Wih0 is countdown)
// Wr1p: k<512: Wih1[g][k] ; k>=512: Whh1[g][k-512]
// ---------------------------------------------------------------------------
__global__ __launch_bounds__(256, 1) void prep_k(
    const float* __restrict__ Wg,  const float* __restrict__ Wih0,
    const float* __restrict__ Whh0,const float* __restrict__ Wih1,
    const float* __restrict__ Whh1,const float* __restrict__ bih0,
    const float* __restrict__ bhh0,const float* __restrict__ bih1,
    const float* __restrict__ bhh1,const float* __restrict__ h0,
    const float* __restrict__ pout,
    unsigned short* __restrict__ WgBf, unsigned short* __restrict__ W0e,
    unsigned short* __restrict__ Wr0p, unsigned short* __restrict__ Wr1p,
    float* __restrict__ b1p, float* __restrict__ bias0c,
    float* __restrict__ wcd, unsigned short* __restrict__ xcat0)
{
  const long N0 = 16384000L;           // WgBf
  const long N1 = N0 + 1048576L;       // W0e
  const long N2 = N1 + 2097152L;       // Wr0p
  const long N3 = N2 + 2097152L;       // Wr1p
  const long N4 = N3 + 2048L;          // b1p
  const long N5 = N4 + 2048L;          // bias0c
  const long N6 = N5 + 2048L;          // wcd
  const long N7 = N6 + 32768L;         // xcat0
  for (long i = blockIdx.x * 256L + threadIdx.x; i < N7; i += 256L * gridDim.x) {
    if (i < N0) {
      WgBf[i] = f2bf(Wg[i]);
    } else if (i < N1) {
      long k = i - N0; int g = (int)(k >> 9); int kk = (int)(k & 511);
      W0e[k] = f2bf(Wih0[g * 1025 + kk]);
    } else if (i < N2) {
      long k = i - N1; int gp = (int)(k >> 10); int kk = (int)(k & 1023);
      int j = gp >> 2, gate = gp & 3; int g = gate * 512 + j;
      float v = (kk < 512) ? Whh0[g * 512 + kk] : Wih0[g * 1025 + 513 + (kk - 512)];
      Wr0p[k] = f2bf(v);
    } else if (i < N3) {
      long k = i - N2; int gp = (int)(k >> 10); int kk = (int)(k & 1023);
      int j = gp >> 2, gate = gp & 3; int g = gate * 512 + j;
      float v = (kk < 512) ? Wih1[g * 512 + kk] : Whh1[g * 512 + (kk - 512)];
      Wr1p[k] = f2bf(v);
    } else if (i < N4) {
      int gp = (int)(i - N3); int j = gp >> 2, gate = gp & 3; int g = gate * 512 + j;
      b1p[gp] = bih1[g] + bhh1[g];
    } else if (i < N5) {
      int g = (int)(i - N4); bias0c[g] = bih0[g] + bhh0[g];
    } else if (i < N6) {
      int g = (int)(i - N5); wcd[g] = Wih0[g * 1025 + 512];
    } else {
      long k = i - N6; int b = (int)(k >> 10); int kk = (int)(k & 1023);
      float v = (kk < 512) ? h0[b * 512 + kk] : pout[b * 512 + (kk - 512)];
      xcat0[k] = f2bf(v);
    }
  }
}

// ---------------------------------------------------------------------------
// embedding: emb_bf[tb][k] = bf16(word_emb[ids[tb]][k] + special_emb[sp][k])
// ---------------------------------------------------------------------------
__global__ __launch_bounds__(256, 1) void emb_k(
    const int* __restrict__ ids, const float* __restrict__ wemb,
    const float* __restrict__ semb, unsigned short* __restrict__ ebf)
{
  const int tb = blockIdx.x;
  const int id = ids[tb];
  const int sp = (id < 3) ? (id + 1) : 0;
  const float* wr = wemb + (long)id * 512;
  const float* sr = semb + sp * 512;
  for (int i = threadIdx.x; i < 512; i += 256)
    ebf[tb * 512 + i] = f2bf(wr[i] + sr[i]);
}

// ---------------------------------------------------------------------------
// GEMM: D[m][n] = sum_k A[m][k]*B[n][k]  (A [M][512] bf16, B [N][512] bf16)
// 128x128 tile, BK=32, 4 waves, global_load_lds(16B) with XOR-swizzled source.
// EPI==0: P0t path — write C[perm(m)][n] + bias0c[m] + cd[n]*wcd[m], N=4096
// EPI==1: generator — write C[m][n] + bg[n]
// ---------------------------------------------------------------------------
template<int EPI>
__global__ __launch_bounds__(256, 1) void gemm_bt(
    const unsigned short* __restrict__ A,
    const unsigned short* __restrict__ B, int N,
    float* __restrict__ C,
    const float* __restrict__ e0, const float* __restrict__ e1,
    const float* __restrict__ e2)
{
  __shared__ unsigned short sA[4096];
  __shared__ unsigned short sB[4096];
  const int tid = threadIdx.x;
  const int l = tid & 63, w = tid >> 6;
  const int nb = N >> 7;
  const int bid = blockIdx.x;
  const int bm = bid / nb, bn = bid - bm * nb;

  // staging: physical 16B chunk u -> (row r=u>>2, pchunk p=u&3), logical c=p^(r&3)
  const int u0 = w * 128 + l;
  const int u1 = u0 + 64;
  const int r0 = u0 >> 2, c0 = (u0 & 3) ^ (r0 & 3);
  const int r1 = u1 >> 2, c1 = (u1 & 3) ^ (r1 & 3);
  const unsigned short* ga0 = A + (long)(bm * 128 + r0) * 512 + c0 * 8;
  const unsigned short* ga1 = A + (long)(bm * 128 + r1) * 512 + c1 * 8;
  const unsigned short* gb0 = B + (long)(bn * 128 + r0) * 512 + c0 * 8;
  const unsigned short* gb1 = B + (long)(bn * 128 + r1) * 512 + c1 * 8;
  unsigned short* la0 = sA + (w * 2 + 0) * 512;
  unsigned short* la1 = sA + (w * 2 + 1) * 512;
  unsigned short* lb0 = sB + (w * 2 + 0) * 512;
  unsigned short* lb1 = sB + (w * 2 + 1) * 512;

  const int fr = l & 15, fc = l >> 4;
  const int wm = w >> 1, wn = w & 1;
  int aoff[4], boff[4];
#pragma unroll
  for (int mi = 0; mi < 4; ++mi) {
    int row = wm * 64 + mi * 16 + fr;
    aoff[mi] = row * 64 + ((fc ^ (row & 3)) * 16);
  }
#pragma unroll
  for (int ni = 0; ni < 4; ++ni) {
    int row = wn * 64 + ni * 16 + fr;
    boff[ni] = row * 64 + ((fc ^ (row & 3)) * 16);
  }

  f32x4 acc[4][4];
#pragma unroll
  for (int i = 0; i < 4; ++i)
#pragma unroll
    for (int jq = 0; jq < 4; ++jq) acc[i][jq] = (f32x4){0.f, 0.f, 0.f, 0.f};

  for (int kt = 0; kt < 16; ++kt) {
    __syncthreads();
    gl16(ga0 + kt * 32, la0);
    gl16(ga1 + kt * 32, la1);
    gl16(gb0 + kt * 32, lb0);
    gl16(gb1 + kt * 32, lb1);
    asm volatile("s_waitcnt vmcnt(0)" ::: "memory");
    __syncthreads();
    bf16x8 av[4], bv[4];
#pragma unroll
    for (int mi = 0; mi < 4; ++mi)
      av[mi] = *(const bf16x8*)((const char*)sA + aoff[mi]);
#pragma unroll
    for (int ni = 0; ni < 4; ++ni)
      bv[ni] = *(const bf16x8*)((const char*)sB + boff[ni]);
#pragma unroll
    for (int mi = 0; mi < 4; ++mi)
#pragma unroll
      for (int ni = 0; ni < 4; ++ni)
        acc[mi][ni] = __builtin_amdgcn_mfma_f32_16x16x32_bf16(av[mi], bv[ni], acc[mi][ni], 0, 0, 0);
  }

  const int mbase = bm * 128 + wm * 64;
  const int nbase = bn * 128 + wn * 64;
#pragma unroll
  for (int mi = 0; mi < 4; ++mi)
#pragma unroll
    for (int ni = 0; ni < 4; ++ni) {
      const int col = nbase + ni * 16 + fr;
#pragma unroll
      for (int r = 0; r < 4; ++r) {
        const int row = mbase + mi * 16 + fc * 4 + r;
        float v = acc[mi][ni][r];
        if (EPI == 0) {
          const int gp = ((row & 511) << 2) | (row >> 9);
          v += e0[row] + e2[col] * e1[row];
          C[(long)gp * N + col] = v;
        } else {
          v += e0[col];
          C[(long)row * N + col] = v;
        }
      }
    }
}

// ---------------------------------------------------------------------------
// Persistent sequential LSTM. 64 WGs x 256 thr. WG owns j in [wg*8, wg*8+8).
// xcat0=[h0_prev | out_prev], xcat1=[h0_new | h1_prev], both [32][1024] bf16.
// Cross-WG traffic via device-scope relaxed atomics (no cache-invalidating
// acquire fences -> weights stay L2-resident). Monotone spin barrier.
// ---------------------------------------------------------------------------
__global__ __launch_bounds__(256, 1) void lstm_seq(
    const unsigned short* __restrict__ Wr0p,
    const unsigned short* __restrict__ Wr1p,
    const float* __restrict__ P0t, const float* __restrict__ b1p,
    const float* __restrict__ h0in, const float* __restrict__ c0in,
    unsigned short* __restrict__ xcat0, unsigned short* __restrict__ xcat1,
    unsigned short* __restrict__ outbf, float* __restrict__ outs,
    unsigned int* __restrict__ bar)
{
  const int tid = threadIdx.x;
  const int wg = blockIdx.x;            // 64
  const int l = tid & 63, w = tid >> 6;
  const int mi = w & 1, ni = w >> 1;
  const int fr = l & 15, fc = l >> 4;

  __shared__ float sg[32][33];

  const int b = tid & 31, jl = tid >> 5; // jl 0..7
  const int j = wg * 8 + jl;

  float c0r = c0in[b * 512 + j];
  float c1r = c0in[16384 + b * 512 + j];
  float h1keep = h0in[16384 + b * 512 + j];
  float h0keep = 0.0f;

  const int arow = (mi * 16 + fr) * 1024 + fc * 8;             // elements
  const int brow = (wg * 32 + ni * 16 + fr) * 1024 + fc * 8;

  unsigned int target = 64;

  for (int t = 0; t < 128; ++t) {
    // ---------------- phase A: layer 0 ----------------
    {
      f32x4 acc = (f32x4){0.f, 0.f, 0.f, 0.f};
#pragma unroll 8
      for (int kt = 0; kt < 32; ++kt) {
        const unsigned long long* ap = (const unsigned long long*)(xcat0 + arow + kt * 32);
        unsigned long long q0 = __hip_atomic_load(ap,     __ATOMIC_RELAXED, __HIP_MEMORY_SCOPE_AGENT);
        unsigned long long q1 = __hip_atomic_load(ap + 1, __ATOMIC_RELAXED, __HIP_MEMORY_SCOPE_AGENT);
        u64x2 qq; qq.x = q0; qq.y = q1;
        bf16x8 av = __builtin_bit_cast(bf16x8, qq);
        bf16x8 bv = *(const bf16x8*)(Wr0p + brow + kt * 32);
        acc = __builtin_amdgcn_mfma_f32_16x16x32_bf16(av, bv, acc, 0, 0, 0);
      }
#pragma unroll
      for (int r = 0; r < 4; ++r) sg[mi * 16 + fc * 4 + r][ni * 16 + fr] = acc[r];
    }
    __syncthreads();
    {
      const int tb = t * 32 + b;
      float gi = sg[b][jl * 4 + 0] + P0t[(j * 4 + 0) * 4096 + tb];
      float gf = sg[b][jl * 4 + 1] + P0t[(j * 4 + 1) * 4096 + tb];
      float gg = sg[b][jl * 4 + 2] + P0t[(j * 4 + 2) * 4096 + tb];
      float go = sg[b][jl * 4 + 3] + P0t[(j * 4 + 3) * 4096 + tb];
      float cn = sigm(gf) * c0r + sigm(gi) * tanhf(gg);
      float hn = sigm(go) * tanhf(cn);
      c0r = cn; h0keep = hn;
      __hip_atomic_store(&xcat1[b * 1024 + j],       f2bf(hn),     __ATOMIC_RELAXED, __HIP_MEMORY_SCOPE_AGENT);
      __hip_atomic_store(&xcat1[b * 1024 + 512 + j], f2bf(h1keep), __ATOMIC_RELAXED, __HIP_MEMORY_SCOPE_AGENT);
    }
    __syncthreads();
    if (tid == 0) {
      __hip_atomic_fetch_add(bar, 1u, __ATOMIC_RELEASE, __HIP_MEMORY_SCOPE_AGENT);
      while (__hip_atomic_load(bar, __ATOMIC_RELAXED, __HIP_MEMORY_SCOPE_AGENT) < target)
        __builtin_amdgcn_s_sleep(1);
    }
    __syncthreads();
    target += 64;

    // ---------------- phase B: layer 1 ----------------
    {
      f32x4 acc = (f32x4){0.f, 0.f, 0.f, 0.f};
#pragma unroll 8
      for (int kt = 0; kt < 32; ++kt) {
        const unsigned long long* ap = (const unsigned long long*)(xcat1 + arow + kt * 32);
        unsigned long long q0 = __hip_atomic_load(ap,     __ATOMIC_RELAXED, __HIP_MEMORY_SCOPE_AGENT);
        unsigned long long q1 = __hip_atomic_load(ap + 1, __ATOMIC_RELAXED, __HIP_MEMORY_SCOPE_AGENT);
        u64x2 qq; qq.x = q0; qq.y = q1;
        bf16x8 av = __builtin_bit_cast(bf16x8, qq);
        bf16x8 bv = *(const bf16x8*)(Wr1p + brow + kt * 32);
        acc = __builtin_amdgcn_mfma_f32_16x16x32_bf16(av, bv, acc, 0, 0, 0);
      }
#pragma unroll
      for (int r = 0; r < 4; ++r) sg[mi * 16 + fc * 4 + r][ni * 16 + fr] = acc[r];
    }
    __syncthreads();
    {
      const int tb = t * 32 + b;
      float gi = sg[b][jl * 4 + 0] + b1p[j * 4 + 0];
      float gf = sg[b][jl * 4 + 1] + b1p[j * 4 + 1];
      float gg = sg[b][jl * 4 + 2] + b1p[j * 4 + 2];
      float go = sg[b][jl * 4 + 3] + b1p[j * 4 + 3];
      float cn = sigm(gf) * c1r + sigm(gi) * tanhf(gg);
      float hn = sigm(go) * tanhf(cn);
      c1r = cn; h1keep = hn;
      __hip_atomic_store(&xcat0[b * 1024 + j],       f2bf(h0keep), __ATOMIC_RELAXED, __HIP_MEMORY_SCOPE_AGENT);
      __hip_atomic_store(&xcat0[b * 1024 + 512 + j], f2bf(hn),     __ATOMIC_RELAXED, __HIP_MEMORY_SCOPE_AGENT);
      outbf[tb * 512 + j] = f2bf(hn);
    }
    __syncthreads();
    if (tid == 0) {
      __hip_atomic_fetch_add(bar, 1u, __ATOMIC_RELEASE, __HIP_MEMORY_SCOPE_AGENT);
      while (__hip_atomic_load(bar, __ATOMIC_RELAXED, __HIP_MEMORY_SCOPE_AGENT) < target)
        __builtin_amdgcn_s_sleep(1);
    }
    __syncthreads();
    target += 64;
  }

  // final state outputs
  float* hT = outs + 131072000;
  float* cT = outs + 131072000 + 32768;
  float* oT = outs + 131072000 + 65536;
  hT[b * 512 + j] = h0keep;
  hT[16384 + b * 512 + j] = h1keep;
  cT[b * 512 + j] = c0r;
  cT[16384 + b * 512 + j] = c1r;
  oT[b * 512 + j] = h1keep;
}

// ---------------------------------------------------------------------------
// per-row online logsumexp + in-place subtract (rows of 32000)
// ---------------------------------------------------------------------------
__global__ __launch_bounds__(256, 1) void lse_fix(float* __restrict__ sc)
{
  const long row = blockIdx.x;
  float* p = sc + row * 32000L;
  const int tid = threadIdx.x;
  float m = -3.0e38f, s = 0.0f;
  for (int i = tid; i < 32000; i += 256) {
    float v = p[i];
    float mn = fmaxf(m, v);
    s = s * __expf(m - mn) + __expf(v - mn);
    m = mn;
  }
#pragma unroll
  for (int off = 32; off > 0; off >>= 1) {
    float mo = __shfl_down(m, off);
    float so = __shfl_down(s, off);
    float mn = fmaxf(m, mo);
    s = s * __expf(m - mn) + so * __expf(mo - mn);
    m = mn;
  }
  __shared__ float lm[4], ls[4], lse_sh;
  if ((tid & 63) == 0) { lm[tid >> 6] = m; ls[tid >> 6] = s; }
  __syncthreads();
  if (tid == 0) {
    float M = lm[0], S = ls[0];
#pragma unroll
    for (int i = 1; i < 4; ++i) {
      float mn = fmaxf(M, lm[i]);
      S = S * __expf(M - mn) + ls[i] * __expf(lm[i] - mn);
      M = mn;
    }
    lse_sh = M + __logf(S);
  }
  __syncthreads();
  const float lse = lse_sh;
  for (int i = tid; i < 32000; i += 256) p[i] -= lse;
}

// ---------------------------------------------------------------------------
extern "C" void kernel_launch(void* const* d_in, const int* in_sizes, int n_in,
                              void* d_out, int out_size, void* d_ws, size_t ws_size,
                              hipStream_t stream) {
  const int*   ids  = (const int*)d_in[0];
  const float* cd   = (const float*)d_in[1];
  const float* wemb = (const float*)d_in[2];
  const float* semb = (const float*)d_in[3];
  const float* h0   = (const float*)d_in[4];
  const float* c0   = (const float*)d_in[5];
  const float* pout = (const float*)d_in[6];
  const float* Wih0 = (const float*)d_in[7];
  const float* Whh0 = (const float*)d_in[8];
  const float* bih0 = (const float*)d_in[9];
  const float* bhh0 = (const float*)d_in[10];
  const float* Wih1 = (const float*)d_in[11];
  const float* Whh1 = (const float*)d_in[12];
  const float* bih1 = (const float*)d_in[13];
  const float* bhh1 = (const float*)d_in[14];
  const float* Wg   = (const float*)d_in[15];
  const float* bg   = (const float*)d_in[16];
  float* out = (float*)d_out;

  char* ws = (char*)d_ws;
  unsigned short* WgBf   = (unsigned short*)(ws);
  unsigned short* W0e    = (unsigned short*)(ws + 32768000);
  unsigned short* Wr0p   = (unsigned short*)(ws + 34865152);
  unsigned short* Wr1p   = (unsigned short*)(ws + 39059456);
  float*          b1p    = (float*)(ws + 43253760);
  float*          bias0c = (float*)(ws + 43261952);
  float*          wcd    = (float*)(ws + 43270144);
  unsigned short* xcat0  = (unsigned short*)(ws + 43278336);
  unsigned short* xcat1  = (unsigned short*)(ws + 43343872);
  unsigned short* embbf  = (unsigned short*)(ws + 43409408);
  unsigned short* outbf  = (unsigned short*)(ws + 47603712);
  float*          P0t    = (float*)(ws + 51798016);
  unsigned int*   bar    = (unsigned int*)(ws + 85352448);

  hipMemsetAsync(bar, 0, 256, stream);

  prep_k<<<8192, 256, 0, stream>>>(Wg, Wih0, Whh0, Wih1, Whh1,
                                   bih0, bhh0, bih1, bhh1, h0, pout,
                                   WgBf, W0e, Wr0p, Wr1p, b1p, bias0c, wcd, xcat0);

  emb_k<<<4096, 256, 0, stream>>>(ids, wemb, semb, embbf);

  // P0t[perm(g)][tb] = W0e @ emb^T + bias0 + cd*wcd   (M=2048, N=4096)
  gemm_bt<0><<<512, 256, 0, stream>>>(W0e, embbf, 4096, P0t, bias0c, wcd, cd);

  lstm_seq<<<64, 256, 0, stream>>>(Wr0p, Wr1p, P0t, b1p, h0, c0,
                                   xcat0, xcat1, outbf, out, bar);

  // logits[tb][v] = out_all @ Wg^T + bg   (M=4096, N=32000) -> d_out scores
  gemm_bt<1><<<8000, 256, 0, stream>>>(outbf, WgBf, 32000, out, bg, nullptr, nullptr);

  lse_fix<<<4096, 256, 0, stream>>>(out);
}

// Round 2
// 4391.425 us; speedup vs baseline: 1.0884x; 1.0884x over previous
//
#include <hip/hip_runtime.h>
#include <hip/hip_bf16.h>

// RNNDecoder: emb -> 2-layer LSTM (seq over T=128) -> generator + log_softmax
// T=128 B=32 E=512 H=512 G=2048 V=32000
//
// R2 change vs R1: barrier fetch_add RELEASE -> RELAXED. Agent-scope release
// on gfx950 emits buffer_wbl2 (full L2 writeback) -- 16K of them accounted for
// WRITE_SIZE=148MB and ~16us/phase. Ordering is already guaranteed by
// __syncthreads()'s s_waitcnt vmcnt(0) (all sc1 stores ack'd at coherence
// point) before the relaxed sc1 RMW on the counter.
//
// ws layout (bytes):
//  [0)            Wg_bf16   [32000][512]            32,768,000
//  [32768000)     W0e_bf16  [2048][512]              2,097,152
//  [34865152)     Wr0p_bf16 [2048][1024]             4,194,304
//  [39059456)     Wr1p_bf16 [2048][1024]             4,194,304
//  [43253760)     b1p f32   [2048]                       8,192
//  [43261952)     bias0c f32[2048]                       8,192
//  [43270144)     wcd f32   [2048]                       8,192
//  [43278336)     xcat0 bf16[32][1024]                  65,536
//  [43343872)     xcat1 bf16[32][1024]                  65,536
//  [43409408)     emb_bf16  [4096][512]              4,194,304
//  [47603712)     out_bf16  [4096][512]              4,194,304
//  [51798016)     P0t f32   [2048][4096]            33,554,432
//  [85352448)     barrier ctr                            256
// total ~85.4 MB

typedef __attribute__((ext_vector_type(8))) short bf16x8;
typedef __attribute__((ext_vector_type(4))) float f32x4;
typedef __attribute__((ext_vector_type(2))) unsigned long long u64x2;

#define AS1 __attribute__((address_space(1)))
#define AS3 __attribute__((address_space(3)))

__device__ __forceinline__ unsigned short f2bf(float f) {
  unsigned int u = __builtin_bit_cast(unsigned int, f);
  u += 0x7fffu + ((u >> 16) & 1u);            // round-to-nearest-even
  return (unsigned short)(u >> 16);
}

__device__ __forceinline__ void gl16(const void* g, void* l) {
  __builtin_amdgcn_global_load_lds((const AS1 unsigned int*)g,
                                   (AS3 unsigned int*)l, 16, 0, 0);
}

__device__ __forceinline__ float sigm(float x) { return 1.0f / (1.0f + __expf(-x)); }

// ---------------------------------------------------------------------------
// prep: dtype conversion + weight re-layout + initial xcat0
// Wr0p[gp][k], gp = 4*j + gate (gate-interleaved), g = gate*512 + j
//   k<512 : Whh0[g][k]      (h_prev part)
//   k>=512: Wih0[g][513+k-512]  (out_prev part; col 512 of Wih0 is countdown)
// Wr1p: k<512: Wih1[g][k] ; k>=512: Whh1[g][k-512]
// ---------------------------------------------------------------------------
__global__ __launch_bounds__(256, 1) void prep_k(
    const float* __restrict__ Wg,  const float* __restrict__ Wih0,
    const float* __restrict__ Whh0,const float* __restrict__ Wih1,
    const float* __restrict__ Whh1,const float* __restrict__ bih0,
    const float* __restrict__ bhh0,const float* __restrict__ bih1,
    const float* __restrict__ bhh1,const float* __restrict__ h0,
    const float* __restrict__ pout,
    unsigned short* __restrict__ WgBf, unsigned short* __restrict__ W0e,
    unsigned short* __restrict__ Wr0p, unsigned short* __restrict__ Wr1p,
    float* __restrict__ b1p, float* __restrict__ bias0c,
    float* __restrict__ wcd, unsigned short* __restrict__ xcat0)
{
  const long N0 = 16384000L;           // WgBf
  const long N1 = N0 + 1048576L;       // W0e
  const long N2 = N1 + 2097152L;       // Wr0p
  const long N3 = N2 + 2097152L;       // Wr1p
  const long N4 = N3 + 2048L;          // b1p
  const long N5 = N4 + 2048L;          // bias0c
  const long N6 = N5 + 2048L;          // wcd
  const long N7 = N6 + 32768L;         // xcat0
  for (long i = blockIdx.x * 256L + threadIdx.x; i < N7; i += 256L * gridDim.x) {
    if (i < N0) {
      WgBf[i] = f2bf(Wg[i]);
    } else if (i < N1) {
      long k = i - N0; int g = (int)(k >> 9); int kk = (int)(k & 511);
      W0e[k] = f2bf(Wih0[g * 1025 + kk]);
    } else if (i < N2) {
      long k = i - N1; int gp = (int)(k >> 10); int kk = (int)(k & 1023);
      int j = gp >> 2, gate = gp & 3; int g = gate * 512 + j;
      float v = (kk < 512) ? Whh0[g * 512 + kk] : Wih0[g * 1025 + 513 + (kk - 512)];
      Wr0p[k] = f2bf(v);
    } else if (i < N3) {
      long k = i - N2; int gp = (int)(k >> 10); int kk = (int)(k & 1023);
      int j = gp >> 2, gate = gp & 3; int g = gate * 512 + j;
      float v = (kk < 512) ? Wih1[g * 512 + kk] : Whh1[g * 512 + (kk - 512)];
      Wr1p[k] = f2bf(v);
    } else if (i < N4) {
      int gp = (int)(i - N3); int j = gp >> 2, gate = gp & 3; int g = gate * 512 + j;
      b1p[gp] = bih1[g] + bhh1[g];
    } else if (i < N5) {
      int g = (int)(i - N4); bias0c[g] = bih0[g] + bhh0[g];
    } else if (i < N6) {
      int g = (int)(i - N5); wcd[g] = Wih0[g * 1025 + 512];
    } else {
      long k = i - N6; int b = (int)(k >> 10); int kk = (int)(k & 1023);
      float v = (kk < 512) ? h0[b * 512 + kk] : pout[b * 512 + (kk - 512)];
      xcat0[k] = f2bf(v);
    }
  }
}

// ---------------------------------------------------------------------------
// embedding: emb_bf[tb][k] = bf16(word_emb[ids[tb]][k] + special_emb[sp][k])
// ---------------------------------------------------------------------------
__global__ __launch_bounds__(256, 1) void emb_k(
    const int* __restrict__ ids, const float* __restrict__ wemb,
    const float* __restrict__ semb, unsigned short* __restrict__ ebf)
{
  const int tb = blockIdx.x;
  const int id = ids[tb];
  const int sp = (id < 3) ? (id + 1) : 0;
  const float* wr = wemb + (long)id * 512;
  const float* sr = semb + sp * 512;
  for (int i = threadIdx.x; i < 512; i += 256)
    ebf[tb * 512 + i] = f2bf(wr[i] + sr[i]);
}

// ---------------------------------------------------------------------------
// GEMM: D[m][n] = sum_k A[m][k]*B[n][k]  (A [M][512] bf16, B [N][512] bf16)
// 128x128 tile, BK=32, 4 waves, global_load_lds(16B) with XOR-swizzled source.
// EPI==0: P0t path — write C[perm(m)][n] + bias0c[m] + cd[n]*wcd[m], N=4096
// EPI==1: generator — write C[m][n] + bg[n]
// ---------------------------------------------------------------------------
template<int EPI>
__global__ __launch_bounds__(256, 1) void gemm_bt(
    const unsigned short* __restrict__ A,
    const unsigned short* __restrict__ B, int N,
    float* __restrict__ C,
    const float* __restrict__ e0, const float* __restrict__ e1,
    const float* __restrict__ e2)
{
  __shared__ unsigned short sA[4096];
  __shared__ unsigned short sB[4096];
  const int tid = threadIdx.x;
  const int l = tid & 63, w = tid >> 6;
  const int nb = N >> 7;
  const int bid = blockIdx.x;
  const int bm = bid / nb, bn = bid - bm * nb;

  // staging: physical 16B chunk u -> (row r=u>>2, pchunk p=u&3), logical c=p^(r&3)
  const int u0 = w * 128 + l;
  const int u1 = u0 + 64;
  const int r0 = u0 >> 2, c0 = (u0 & 3) ^ (r0 & 3);
  const int r1 = u1 >> 2, c1 = (u1 & 3) ^ (r1 & 3);
  const unsigned short* ga0 = A + (long)(bm * 128 + r0) * 512 + c0 * 8;
  const unsigned short* ga1 = A + (long)(bm * 128 + r1) * 512 + c1 * 8;
  const unsigned short* gb0 = B + (long)(bn * 128 + r0) * 512 + c0 * 8;
  const unsigned short* gb1 = B + (long)(bn * 128 + r1) * 512 + c1 * 8;
  unsigned short* la0 = sA + (w * 2 + 0) * 512;
  unsigned short* la1 = sA + (w * 2 + 1) * 512;
  unsigned short* lb0 = sB + (w * 2 + 0) * 512;
  unsigned short* lb1 = sB + (w * 2 + 1) * 512;

  const int fr = l & 15, fc = l >> 4;
  const int wm = w >> 1, wn = w & 1;
  int aoff[4], boff[4];
#pragma unroll
  for (int mi = 0; mi < 4; ++mi) {
    int row = wm * 64 + mi * 16 + fr;
    aoff[mi] = row * 64 + ((fc ^ (row & 3)) * 16);
  }
#pragma unroll
  for (int ni = 0; ni < 4; ++ni) {
    int row = wn * 64 + ni * 16 + fr;
    boff[ni] = row * 64 + ((fc ^ (row & 3)) * 16);
  }

  f32x4 acc[4][4];
#pragma unroll
  for (int i = 0; i < 4; ++i)
#pragma unroll
    for (int jq = 0; jq < 4; ++jq) acc[i][jq] = (f32x4){0.f, 0.f, 0.f, 0.f};

  for (int kt = 0; kt < 16; ++kt) {
    __syncthreads();
    gl16(ga0 + kt * 32, la0);
    gl16(ga1 + kt * 32, la1);
    gl16(gb0 + kt * 32, lb0);
    gl16(gb1 + kt * 32, lb1);
    asm volatile("s_waitcnt vmcnt(0)" ::: "memory");
    __syncthreads();
    bf16x8 av[4], bv[4];
#pragma unroll
    for (int mi = 0; mi < 4; ++mi)
      av[mi] = *(const bf16x8*)((const char*)sA + aoff[mi]);
#pragma unroll
    for (int ni = 0; ni < 4; ++ni)
      bv[ni] = *(const bf16x8*)((const char*)sB + boff[ni]);
#pragma unroll
    for (int mi = 0; mi < 4; ++mi)
#pragma unroll
      for (int ni = 0; ni < 4; ++ni)
        acc[mi][ni] = __builtin_amdgcn_mfma_f32_16x16x32_bf16(av[mi], bv[ni], acc[mi][ni], 0, 0, 0);
  }

  const int mbase = bm * 128 + wm * 64;
  const int nbase = bn * 128 + wn * 64;
#pragma unroll
  for (int mi = 0; mi < 4; ++mi)
#pragma unroll
    for (int ni = 0; ni < 4; ++ni) {
      const int col = nbase + ni * 16 + fr;
#pragma unroll
      for (int r = 0; r < 4; ++r) {
        const int row = mbase + mi * 16 + fc * 4 + r;
        float v = acc[mi][ni][r];
        if (EPI == 0) {
          const int gp = ((row & 511) << 2) | (row >> 9);
          v += e0[row] + e2[col] * e1[row];
          C[(long)gp * N + col] = v;
        } else {
          v += e0[col];
          C[(long)row * N + col] = v;
        }
      }
    }
}

// ---------------------------------------------------------------------------
// Persistent sequential LSTM. 64 WGs x 256 thr. WG owns j in [wg*8, wg*8+8).
// xcat0=[h0_prev | out_prev], xcat1=[h0_new | h1_prev], both [32][1024] bf16.
// Cross-WG traffic via agent-scope RELAXED atomics (sc1 -> coherence point;
// no buffer_wbl2 from release, no buffer_inv from acquire). Ordering for the
// barrier comes from __syncthreads()'s s_waitcnt vmcnt(0): all sc1 data
// stores are ack'd at the coherence point before tid0's relaxed RMW.
// ---------------------------------------------------------------------------
__global__ __launch_bounds__(256, 1) void lstm_seq(
    const unsigned short* __restrict__ Wr0p,
    const unsigned short* __restrict__ Wr1p,
    const float* __restrict__ P0t, const float* __restrict__ b1p,
    const float* __restrict__ h0in, const float* __restrict__ c0in,
    unsigned short* __restrict__ xcat0, unsigned short* __restrict__ xcat1,
    unsigned short* __restrict__ outbf, float* __restrict__ outs,
    unsigned int* __restrict__ bar)
{
  const int tid = threadIdx.x;
  const int wg = blockIdx.x;            // 64
  const int l = tid & 63, w = tid >> 6;
  const int mi = w & 1, ni = w >> 1;
  const int fr = l & 15, fc = l >> 4;

  __shared__ float sg[32][33];

  const int b = tid & 31, jl = tid >> 5; // jl 0..7
  const int j = wg * 8 + jl;

  float c0r = c0in[b * 512 + j];
  float c1r = c0in[16384 + b * 512 + j];
  float h1keep = h0in[16384 + b * 512 + j];
  float h0keep = 0.0f;

  const int arow = (mi * 16 + fr) * 1024 + fc * 8;             // elements
  const int brow = (wg * 32 + ni * 16 + fr) * 1024 + fc * 8;

  unsigned int target = 64;

  for (int t = 0; t < 128; ++t) {
    // ---------------- phase A: layer 0 ----------------
    {
      f32x4 acc = (f32x4){0.f, 0.f, 0.f, 0.f};
#pragma unroll 8
      for (int kt = 0; kt < 32; ++kt) {
        const unsigned long long* ap = (const unsigned long long*)(xcat0 + arow + kt * 32);
        unsigned long long q0 = __hip_atomic_load(ap,     __ATOMIC_RELAXED, __HIP_MEMORY_SCOPE_AGENT);
        unsigned long long q1 = __hip_atomic_load(ap + 1, __ATOMIC_RELAXED, __HIP_MEMORY_SCOPE_AGENT);
        u64x2 qq; qq.x = q0; qq.y = q1;
        bf16x8 av = __builtin_bit_cast(bf16x8, qq);
        bf16x8 bv = *(const bf16x8*)(Wr0p + brow + kt * 32);
        acc = __builtin_amdgcn_mfma_f32_16x16x32_bf16(av, bv, acc, 0, 0, 0);
      }
#pragma unroll
      for (int r = 0; r < 4; ++r) sg[mi * 16 + fc * 4 + r][ni * 16 + fr] = acc[r];
    }
    __syncthreads();
    {
      const int tb = t * 32 + b;
      float gi = sg[b][jl * 4 + 0] + P0t[(j * 4 + 0) * 4096 + tb];
      float gf = sg[b][jl * 4 + 1] + P0t[(j * 4 + 1) * 4096 + tb];
      float gg = sg[b][jl * 4 + 2] + P0t[(j * 4 + 2) * 4096 + tb];
      float go = sg[b][jl * 4 + 3] + P0t[(j * 4 + 3) * 4096 + tb];
      float cn = sigm(gf) * c0r + sigm(gi) * tanhf(gg);
      float hn = sigm(go) * tanhf(cn);
      c0r = cn; h0keep = hn;
      __hip_atomic_store(&xcat1[b * 1024 + j],       f2bf(hn),     __ATOMIC_RELAXED, __HIP_MEMORY_SCOPE_AGENT);
      __hip_atomic_store(&xcat1[b * 1024 + 512 + j], f2bf(h1keep), __ATOMIC_RELAXED, __HIP_MEMORY_SCOPE_AGENT);
    }
    __syncthreads();
    if (tid == 0) {
      __hip_atomic_fetch_add(bar, 1u, __ATOMIC_RELAXED, __HIP_MEMORY_SCOPE_AGENT);
      while (__hip_atomic_load(bar, __ATOMIC_RELAXED, __HIP_MEMORY_SCOPE_AGENT) < target)
        __builtin_amdgcn_s_sleep(1);
    }
    __syncthreads();
    target += 64;

    // ---------------- phase B: layer 1 ----------------
    {
      f32x4 acc = (f32x4){0.f, 0.f, 0.f, 0.f};
#pragma unroll 8
      for (int kt = 0; kt < 32; ++kt) {
        const unsigned long long* ap = (const unsigned long long*)(xcat1 + arow + kt * 32);
        unsigned long long q0 = __hip_atomic_load(ap,     __ATOMIC_RELAXED, __HIP_MEMORY_SCOPE_AGENT);
        unsigned long long q1 = __hip_atomic_load(ap + 1, __ATOMIC_RELAXED, __HIP_MEMORY_SCOPE_AGENT);
        u64x2 qq; qq.x = q0; qq.y = q1;
        bf16x8 av = __builtin_bit_cast(bf16x8, qq);
        bf16x8 bv = *(const bf16x8*)(Wr1p + brow + kt * 32);
        acc = __builtin_amdgcn_mfma_f32_16x16x32_bf16(av, bv, acc, 0, 0, 0);
      }
#pragma unroll
      for (int r = 0; r < 4; ++r) sg[mi * 16 + fc * 4 + r][ni * 16 + fr] = acc[r];
    }
    __syncthreads();
    {
      const int tb = t * 32 + b;
      float gi = sg[b][jl * 4 + 0] + b1p[j * 4 + 0];
      float gf = sg[b][jl * 4 + 1] + b1p[j * 4 + 1];
      float gg = sg[b][jl * 4 + 2] + b1p[j * 4 + 2];
      float go = sg[b][jl * 4 + 3] + b1p[j * 4 + 3];
      float cn = sigm(gf) * c1r + sigm(gi) * tanhf(gg);
      float hn = sigm(go) * tanhf(cn);
      c1r = cn; h1keep = hn;
      __hip_atomic_store(&xcat0[b * 1024 + j],       f2bf(h0keep), __ATOMIC_RELAXED, __HIP_MEMORY_SCOPE_AGENT);
      __hip_atomic_store(&xcat0[b * 1024 + 512 + j], f2bf(hn),     __ATOMIC_RELAXED, __HIP_MEMORY_SCOPE_AGENT);
      outbf[tb * 512 + j] = f2bf(hn);
    }
    __syncthreads();
    if (tid == 0) {
      __hip_atomic_fetch_add(bar, 1u, __ATOMIC_RELAXED, __HIP_MEMORY_SCOPE_AGENT);
      while (__hip_atomic_load(bar, __ATOMIC_RELAXED, __HIP_MEMORY_SCOPE_AGENT) < target)
        __builtin_amdgcn_s_sleep(1);
    }
    __syncthreads();
    target += 64;
  }

  // final state outputs
  float* hT = outs + 131072000;
  float* cT = outs + 131072000 + 32768;
  float* oT = outs + 131072000 + 65536;
  hT[b * 512 + j] = h0keep;
  hT[16384 + b * 512 + j] = h1keep;
  cT[b * 512 + j] = c0r;
  cT[16384 + b * 512 + j] = c1r;
  oT[b * 512 + j] = h1keep;
}

// ---------------------------------------------------------------------------
// per-row online logsumexp + in-place subtract (rows of 32000)
// ---------------------------------------------------------------------------
__global__ __launch_bounds__(256, 1) void lse_fix(float* __restrict__ sc)
{
  const long row = blockIdx.x;
  float* p = sc + row * 32000L;
  const int tid = threadIdx.x;
  float m = -3.0e38f, s = 0.0f;
  for (int i = tid; i < 32000; i += 256) {
    float v = p[i];
    float mn = fmaxf(m, v);
    s = s * __expf(m - mn) + __expf(v - mn);
    m = mn;
  }
#pragma unroll
  for (int off = 32; off > 0; off >>= 1) {
    float mo = __shfl_down(m, off);
    float so = __shfl_down(s, off);
    float mn = fmaxf(m, mo);
    s = s * __expf(m - mn) + so * __expf(mo - mn);
    m = mn;
  }
  __shared__ float lm[4], ls[4], lse_sh;
  if ((tid & 63) == 0) { lm[tid >> 6] = m; ls[tid >> 6] = s; }
  __syncthreads();
  if (tid == 0) {
    float M = lm[0], S = ls[0];
#pragma unroll
    for (int i = 1; i < 4; ++i) {
      float mn = fmaxf(M, lm[i]);
      S = S * __expf(M - mn) + ls[i] * __expf(lm[i] - mn);
      M = mn;
    }
    lse_sh = M + __logf(S);
  }
  __syncthreads();
  const float lse = lse_sh;
  for (int i = tid; i < 32000; i += 256) p[i] -= lse;
}

// ---------------------------------------------------------------------------
extern "C" void kernel_launch(void* const* d_in, const int* in_sizes, int n_in,
                              void* d_out, int out_size, void* d_ws, size_t ws_size,
                              hipStream_t stream) {
  const int*   ids  = (const int*)d_in[0];
  const float* cd   = (const float*)d_in[1];
  const float* wemb = (const float*)d_in[2];
  const float* semb = (const float*)d_in[3];
  const float* h0   = (const float*)d_in[4];
  const float* c0   = (const float*)d_in[5];
  const float* pout = (const float*)d_in[6];
  const float* Wih0 = (const float*)d_in[7];
  const float* Whh0 = (const float*)d_in[8];
  const float* bih0 = (const float*)d_in[9];
  const float* bhh0 = (const float*)d_in[10];
  const float* Wih1 = (const float*)d_in[11];
  const float* Whh1 = (const float*)d_in[12];
  const float* bih1 = (const float*)d_in[13];
  const float* bhh1 = (const float*)d_in[14];
  const float* Wg   = (const float*)d_in[15];
  const float* bg   = (const float*)d_in[16];
  float* out = (float*)d_out;

  char* ws = (char*)d_ws;
  unsigned short* WgBf   = (unsigned short*)(ws);
  unsigned short* W0e    = (unsigned short*)(ws + 32768000);
  unsigned short* Wr0p   = (unsigned short*)(ws + 34865152);
  unsigned short* Wr1p   = (unsigned short*)(ws + 39059456);
  float*          b1p    = (float*)(ws + 43253760);
  float*          bias0c = (float*)(ws + 43261952);
  float*          wcd    = (float*)(ws + 43270144);
  unsigned short* xcat0  = (unsigned short*)(ws + 43278336);
  unsigned short* xcat1  = (unsigned short*)(ws + 43343872);
  unsigned short* embbf  = (unsigned short*)(ws + 43409408);
  unsigned short* outbf  = (unsigned short*)(ws + 47603712);
  float*          P0t    = (float*)(ws + 51798016);
  unsigned int*   bar    = (unsigned int*)(ws + 85352448);

  hipMemsetAsync(bar, 0, 256, stream);

  prep_k<<<8192, 256, 0, stream>>>(Wg, Wih0, Whh0, Wih1, Whh1,
                                   bih0, bhh0, bih1, bhh1, h0, pout,
                                   WgBf, W0e, Wr0p, Wr1p, b1p, bias0c, wcd, xcat0);

  emb_k<<<4096, 256, 0, stream>>>(ids, wemb, semb, embbf);

  // P0t[perm(g)][tb] = W0e @ emb^T + bias0 + cd*wcd   (M=2048, N=4096)
  gemm_bt<0><<<512, 256, 0, stream>>>(W0e, embbf, 4096, P0t, bias0c, wcd, cd);

  lstm_seq<<<64, 256, 0, stream>>>(Wr0p, Wr1p, P0t, b1p, h0, c0,
                                   xcat0, xcat1, outbf, out, bar);

  // logits[tb][v] = out_all @ Wg^T + bg   (M=4096, N=32000) -> d_out scores
  gemm_bt<1><<<8000, 256, 0, stream>>>(outbf, WgBf, 32000, out, bg, nullptr, nullptr);

  lse_fix<<<4096, 256, 0, stream>>>(out);
}

// Round 3
// 2701.596 us; speedup vs baseline: 1.7692x; 1.6255x over previous
//
#include <hip/hip_runtime.h>
#include <hip/hip_bf16.h>

// RNNDecoder: emb -> 2-layer LSTM (seq over T=128) -> generator + log_softmax
// T=128 B=32 E=512 H=512 G=2048 V=32000
//
// R3 changes (lstm_seq only):
//  - xcat consumer reads: LDS-staged ONCE per phase (was 2x duplicated,
//    scattered 8B atomic fragment reads) with coalesced sc1 loads and
//    XOR-swizzled LDS layout; MFMA A-frags read from LDS.
//  - xcat produce: LDS-gathered, one wave stores 64x16B dense (was 128x4B
//    scattered), vmcnt-drained, then per-WG flag store.
//  - barrier: per-WG flag array (wave-gather poll, __all) instead of a
//    single hot RMW counter.
//  - P0t prefetched before the poll; b1p hoisted out of the t-loop.
//
// ws layout (bytes):
//  [0)            Wg_bf16   [32000][512]            32,768,000
//  [32768000)     W0e_bf16  [2048][512]              2,097,152
//  [34865152)     Wr0p_bf16 [2048][1024]             4,194,304
//  [39059456)     Wr1p_bf16 [2048][1024]             4,194,304
//  [43253760)     b1p f32   [2048]                       8,192
//  [43261952)     bias0c f32[2048]                       8,192
//  [43270144)     wcd f32   [2048]                       8,192
//  [43278336)     xcat0 bf16[32][1024]                  65,536
//  [43343872)     xcat1 bf16[32][1024]                  65,536
//  [43409408)     emb_bf16  [4096][512]              4,194,304
//  [47603712)     out_bf16  [4096][512]              4,194,304
//  [51798016)     P0t f32   [2048][4096]            33,554,432
//  [85352448)     flagA[64], flagB[64] u32               512
// total ~85.4 MB

typedef __attribute__((ext_vector_type(8))) short bf16x8;
typedef __attribute__((ext_vector_type(4))) float f32x4;

#define AS1 __attribute__((address_space(1)))
#define AS3 __attribute__((address_space(3)))

__device__ __forceinline__ unsigned short f2bf(float f) {
  unsigned int u = __builtin_bit_cast(unsigned int, f);
  u += 0x7fffu + ((u >> 16) & 1u);            // round-to-nearest-even
  return (unsigned short)(u >> 16);
}

__device__ __forceinline__ void gl16(const void* g, void* l) {
  __builtin_amdgcn_global_load_lds((const AS1 unsigned int*)g,
                                   (AS3 unsigned int*)l, 16, 0, 0);
}

__device__ __forceinline__ float sigm(float x) { return 1.0f / (1.0f + __expf(-x)); }

// ---------------------------------------------------------------------------
// prep: dtype conversion + weight re-layout + initial xcat0
// ---------------------------------------------------------------------------
__global__ __launch_bounds__(256, 1) void prep_k(
    const float* __restrict__ Wg,  const float* __restrict__ Wih0,
    const float* __restrict__ Whh0,const float* __restrict__ Wih1,
    const float* __restrict__ Whh1,const float* __restrict__ bih0,
    const float* __restrict__ bhh0,const float* __restrict__ bih1,
    const float* __restrict__ bhh1,const float* __restrict__ h0,
    const float* __restrict__ pout,
    unsigned short* __restrict__ WgBf, unsigned short* __restrict__ W0e,
    unsigned short* __restrict__ Wr0p, unsigned short* __restrict__ Wr1p,
    float* __restrict__ b1p, float* __restrict__ bias0c,
    float* __restrict__ wcd, unsigned short* __restrict__ xcat0)
{
  const long N0 = 16384000L;           // WgBf
  const long N1 = N0 + 1048576L;       // W0e
  const long N2 = N1 + 2097152L;       // Wr0p
  const long N3 = N2 + 2097152L;       // Wr1p
  const long N4 = N3 + 2048L;          // b1p
  const long N5 = N4 + 2048L;          // bias0c
  const long N6 = N5 + 2048L;          // wcd
  const long N7 = N6 + 32768L;         // xcat0
  for (long i = blockIdx.x * 256L + threadIdx.x; i < N7; i += 256L * gridDim.x) {
    if (i < N0) {
      WgBf[i] = f2bf(Wg[i]);
    } else if (i < N1) {
      long k = i - N0; int g = (int)(k >> 9); int kk = (int)(k & 511);
      W0e[k] = f2bf(Wih0[g * 1025 + kk]);
    } else if (i < N2) {
      long k = i - N1; int gp = (int)(k >> 10); int kk = (int)(k & 1023);
      int j = gp >> 2, gate = gp & 3; int g = gate * 512 + j;
      float v = (kk < 512) ? Whh0[g * 512 + kk] : Wih0[g * 1025 + 513 + (kk - 512)];
      Wr0p[k] = f2bf(v);
    } else if (i < N3) {
      long k = i - N2; int gp = (int)(k >> 10); int kk = (int)(k & 1023);
      int j = gp >> 2, gate = gp & 3; int g = gate * 512 + j;
      float v = (kk < 512) ? Wih1[g * 512 + kk] : Whh1[g * 512 + (kk - 512)];
      Wr1p[k] = f2bf(v);
    } else if (i < N4) {
      int gp = (int)(i - N3); int j = gp >> 2, gate = gp & 3; int g = gate * 512 + j;
      b1p[gp] = bih1[g] + bhh1[g];
    } else if (i < N5) {
      int g = (int)(i - N4); bias0c[g] = bih0[g] + bhh0[g];
    } else if (i < N6) {
      int g = (int)(i - N5); wcd[g] = Wih0[g * 1025 + 512];
    } else {
      long k = i - N6; int b = (int)(k >> 10); int kk = (int)(k & 1023);
      float v = (kk < 512) ? h0[b * 512 + kk] : pout[b * 512 + (kk - 512)];
      xcat0[k] = f2bf(v);
    }
  }
}

// ---------------------------------------------------------------------------
// embedding
// ---------------------------------------------------------------------------
__global__ __launch_bounds__(256, 1) void emb_k(
    const int* __restrict__ ids, const float* __restrict__ wemb,
    const float* __restrict__ semb, unsigned short* __restrict__ ebf)
{
  const int tb = blockIdx.x;
  const int id = ids[tb];
  const int sp = (id < 3) ? (id + 1) : 0;
  const float* wr = wemb + (long)id * 512;
  const float* sr = semb + sp * 512;
  for (int i = threadIdx.x; i < 512; i += 256)
    ebf[tb * 512 + i] = f2bf(wr[i] + sr[i]);
}

// ---------------------------------------------------------------------------
// GEMM: D[m][n] = sum_k A[m][k]*B[n][k]  (A [M][512] bf16, B [N][512] bf16)
// ---------------------------------------------------------------------------
template<int EPI>
__global__ __launch_bounds__(256, 1) void gemm_bt(
    const unsigned short* __restrict__ A,
    const unsigned short* __restrict__ B, int N,
    float* __restrict__ C,
    const float* __restrict__ e0, const float* __restrict__ e1,
    const float* __restrict__ e2)
{
  __shared__ unsigned short sA[4096];
  __shared__ unsigned short sB[4096];
  const int tid = threadIdx.x;
  const int l = tid & 63, w = tid >> 6;
  const int nb = N >> 7;
  const int bid = blockIdx.x;
  const int bm = bid / nb, bn = bid - bm * nb;

  const int u0 = w * 128 + l;
  const int u1 = u0 + 64;
  const int r0 = u0 >> 2, c0 = (u0 & 3) ^ (r0 & 3);
  const int r1 = u1 >> 2, c1 = (u1 & 3) ^ (r1 & 3);
  const unsigned short* ga0 = A + (long)(bm * 128 + r0) * 512 + c0 * 8;
  const unsigned short* ga1 = A + (long)(bm * 128 + r1) * 512 + c1 * 8;
  const unsigned short* gb0 = B + (long)(bn * 128 + r0) * 512 + c0 * 8;
  const unsigned short* gb1 = B + (long)(bn * 128 + r1) * 512 + c1 * 8;
  unsigned short* la0 = sA + (w * 2 + 0) * 512;
  unsigned short* la1 = sA + (w * 2 + 1) * 512;
  unsigned short* lb0 = sB + (w * 2 + 0) * 512;
  unsigned short* lb1 = sB + (w * 2 + 1) * 512;

  const int fr = l & 15, fc = l >> 4;
  const int wm = w >> 1, wn = w & 1;
  int aoff[4], boff[4];
#pragma unroll
  for (int mi = 0; mi < 4; ++mi) {
    int row = wm * 64 + mi * 16 + fr;
    aoff[mi] = row * 64 + ((fc ^ (row & 3)) * 16);
  }
#pragma unroll
  for (int ni = 0; ni < 4; ++ni) {
    int row = wn * 64 + ni * 16 + fr;
    boff[ni] = row * 64 + ((fc ^ (row & 3)) * 16);
  }

  f32x4 acc[4][4];
#pragma unroll
  for (int i = 0; i < 4; ++i)
#pragma unroll
    for (int jq = 0; jq < 4; ++jq) acc[i][jq] = (f32x4){0.f, 0.f, 0.f, 0.f};

  for (int kt = 0; kt < 16; ++kt) {
    __syncthreads();
    gl16(ga0 + kt * 32, la0);
    gl16(ga1 + kt * 32, la1);
    gl16(gb0 + kt * 32, lb0);
    gl16(gb1 + kt * 32, lb1);
    asm volatile("s_waitcnt vmcnt(0)" ::: "memory");
    __syncthreads();
    bf16x8 av[4], bv[4];
#pragma unroll
    for (int mi = 0; mi < 4; ++mi)
      av[mi] = *(const bf16x8*)((const char*)sA + aoff[mi]);
#pragma unroll
    for (int ni = 0; ni < 4; ++ni)
      bv[ni] = *(const bf16x8*)((const char*)sB + boff[ni]);
#pragma unroll
    for (int mi = 0; mi < 4; ++mi)
#pragma unroll
      for (int ni = 0; ni < 4; ++ni)
        acc[mi][ni] = __builtin_amdgcn_mfma_f32_16x16x32_bf16(av[mi], bv[ni], acc[mi][ni], 0, 0, 0);
  }

  const int mbase = bm * 128 + wm * 64;
  const int nbase = bn * 128 + wn * 64;
#pragma unroll
  for (int mi = 0; mi < 4; ++mi)
#pragma unroll
    for (int ni = 0; ni < 4; ++ni) {
      const int col = nbase + ni * 16 + fr;
#pragma unroll
      for (int r = 0; r < 4; ++r) {
        const int row = mbase + mi * 16 + fc * 4 + r;
        float v = acc[mi][ni][r];
        if (EPI == 0) {
          const int gp = ((row & 511) << 2) | (row >> 9);
          v += e0[row] + e2[col] * e1[row];
          C[(long)gp * N + col] = v;
        } else {
          v += e0[col];
          C[(long)row * N + col] = v;
        }
      }
    }
}

// ---------------------------------------------------------------------------
// Persistent sequential LSTM. 64 WGs x 256 thr. WG owns j in [wg*8, wg*8+8).
// xcat0=[h0_prev | h1_prev], xcat1=[h0_new | h1_prev], both [32][1024] bf16.
// Per-phase: poll flags -> stage xcat into LDS (coalesced sc1, XOR swizzle)
// -> MFMA (A from LDS, B=weights from L2) -> gates -> dense 16B produce ->
// vmcnt drain -> flag store.
// ---------------------------------------------------------------------------
__global__ __launch_bounds__(256, 1) void lstm_seq(
    const unsigned short* __restrict__ Wr0p,
    const unsigned short* __restrict__ Wr1p,
    const float* __restrict__ P0t, const float* __restrict__ b1p,
    const float* __restrict__ h0in, const float* __restrict__ c0in,
    unsigned short* __restrict__ xcat0, unsigned short* __restrict__ xcat1,
    unsigned short* __restrict__ outbf, float* __restrict__ outs,
    unsigned int* __restrict__ flagA, unsigned int* __restrict__ flagB)
{
  const int tid = threadIdx.x;
  const int wg = blockIdx.x;            // 64
  const int l = tid & 63, w = tid >> 6;
  const int mi = w & 1, ni = w >> 1;
  const int fr = l & 15, fc = l >> 4;

  __shared__ unsigned short sx[32768];  // 64KB staged x, XOR-swizzled
  __shared__ float sg[32][33];
  __shared__ unsigned short sh[32][16]; // [b][0:8]=half0 slice, [8:16]=half1

  const int b = tid & 31, jl = tid >> 5; // jl 0..7
  const int j = wg * 8 + jl;

  float c0r = c0in[b * 512 + j];
  float c1r = c0in[16384 + b * 512 + j];
  float h1keep = h0in[16384 + b * 512 + j];
  float h0keep = 0.0f;

  // bias for layer1 (constant across t)
  float b1v0 = b1p[j * 4 + 0], b1v1 = b1p[j * 4 + 1];
  float b1v2 = b1p[j * 4 + 2], b1v3 = b1p[j * 4 + 3];

  // MFMA fragment addressing
  const int xrow = mi * 16 + fr;                    // b-row for A frag
  const char* sxb = (const char*)sx + xrow * 2048;
  const int xr = (xrow & 7) << 4;                   // swizzle XOR (bits 4..6)
  const int brow = (wg * 32 + ni * 16 + fr) * 1024 + fc * 8;  // weight row

  // produce-side (wave 0): lane l -> (bb, hh)
  const int bb = l >> 1, hh = l & 1;

  for (int t = 0; t < 128; ++t) {
    // ================= phase A: layer 0 =================
    // P0t prefetch (independent of the exchange)
    float p0a = P0t[(j * 4 + 0) * 4096 + t * 32 + b];
    float p0b = P0t[(j * 4 + 1) * 4096 + t * 32 + b];
    float p0c = P0t[(j * 4 + 2) * 4096 + t * 32 + b];
    float p0d = P0t[(j * 4 + 3) * 4096 + t * 32 + b];

    if (w == 0) {
      for (;;) {
        unsigned int f = __hip_atomic_load(&flagB[l], __ATOMIC_RELAXED, __HIP_MEMORY_SCOPE_AGENT);
        if (__all((int)(f >= (unsigned int)t))) break;
        __builtin_amdgcn_s_sleep(2);
      }
    }
    __syncthreads();

    // stage xcat0 -> sx (coalesced: 32 iters x 256 thr x 8B, one row/iter)
    {
      unsigned long long r[32];
#pragma unroll
      for (int i = 0; i < 32; ++i)
        r[i] = __hip_atomic_load((const unsigned long long*)xcat0 + i * 256 + tid,
                                 __ATOMIC_RELAXED, __HIP_MEMORY_SCOPE_AGENT);
#pragma unroll
      for (int i = 0; i < 32; ++i)
        *(unsigned long long*)((char*)sx + i * 2048 + ((tid * 8) ^ ((i & 7) << 4))) = r[i];
    }
    __syncthreads();

    {
      f32x4 acc = (f32x4){0.f, 0.f, 0.f, 0.f};
#pragma unroll 8
      for (int kt = 0; kt < 32; ++kt) {
        bf16x8 av = *(const bf16x8*)(sxb + ((fc * 16 + kt * 64) ^ xr));
        bf16x8 bv = *(const bf16x8*)(Wr0p + brow + kt * 32);
        acc = __builtin_amdgcn_mfma_f32_16x16x32_bf16(av, bv, acc, 0, 0, 0);
      }
#pragma unroll
      for (int r = 0; r < 4; ++r) sg[mi * 16 + fc * 4 + r][ni * 16 + fr] = acc[r];
    }
    __syncthreads();
    {
      float gi = sg[b][jl * 4 + 0] + p0a;
      float gf = sg[b][jl * 4 + 1] + p0b;
      float gg = sg[b][jl * 4 + 2] + p0c;
      float go = sg[b][jl * 4 + 3] + p0d;
      float cn = sigm(gf) * c0r + sigm(gi) * tanhf(gg);
      float hn = sigm(go) * tanhf(cn);
      c0r = cn; h0keep = hn;
      sh[b][jl] = f2bf(hn);          // xcat1 half0 = h0_new
      sh[b][8 + jl] = f2bf(h1keep);  // xcat1 half1 = h1_prev
    }
    __syncthreads();
    if (w == 0) {
      unsigned long long v0 = *(const unsigned long long*)&sh[bb][hh * 8];
      unsigned long long v1 = *(const unsigned long long*)&sh[bb][hh * 8 + 4];
      unsigned long long* dst = (unsigned long long*)(xcat1 + bb * 1024 + hh * 512 + wg * 8);
      __hip_atomic_store(dst,     v0, __ATOMIC_RELAXED, __HIP_MEMORY_SCOPE_AGENT);
      __hip_atomic_store(dst + 1, v1, __ATOMIC_RELAXED, __HIP_MEMORY_SCOPE_AGENT);
      asm volatile("s_waitcnt vmcnt(0)" ::: "memory");
      if (tid == 0)
        __hip_atomic_store(&flagA[wg], (unsigned int)(t + 1), __ATOMIC_RELAXED, __HIP_MEMORY_SCOPE_AGENT);
    }

    // ================= phase B: layer 1 =================
    if (w == 0) {
      for (;;) {
        unsigned int f = __hip_atomic_load(&flagA[l], __ATOMIC_RELAXED, __HIP_MEMORY_SCOPE_AGENT);
        if (__all((int)(f >= (unsigned int)(t + 1)))) break;
        __builtin_amdgcn_s_sleep(2);
      }
    }
    __syncthreads();

    {
      unsigned long long r[32];
#pragma unroll
      for (int i = 0; i < 32; ++i)
        r[i] = __hip_atomic_load((const unsigned long long*)xcat1 + i * 256 + tid,
                                 __ATOMIC_RELAXED, __HIP_MEMORY_SCOPE_AGENT);
#pragma unroll
      for (int i = 0; i < 32; ++i)
        *(unsigned long long*)((char*)sx + i * 2048 + ((tid * 8) ^ ((i & 7) << 4))) = r[i];
    }
    __syncthreads();

    {
      f32x4 acc = (f32x4){0.f, 0.f, 0.f, 0.f};
#pragma unroll 8
      for (int kt = 0; kt < 32; ++kt) {
        bf16x8 av = *(const bf16x8*)(sxb + ((fc * 16 + kt * 64) ^ xr));
        bf16x8 bv = *(const bf16x8*)(Wr1p + brow + kt * 32);
        acc = __builtin_amdgcn_mfma_f32_16x16x32_bf16(av, bv, acc, 0, 0, 0);
      }
#pragma unroll
      for (int r = 0; r < 4; ++r) sg[mi * 16 + fc * 4 + r][ni * 16 + fr] = acc[r];
    }
    __syncthreads();
    {
      float gi = sg[b][jl * 4 + 0] + b1v0;
      float gf = sg[b][jl * 4 + 1] + b1v1;
      float gg = sg[b][jl * 4 + 2] + b1v2;
      float go = sg[b][jl * 4 + 3] + b1v3;
      float cn = sigm(gf) * c1r + sigm(gi) * tanhf(gg);
      float hn = sigm(go) * tanhf(cn);
      c1r = cn; h1keep = hn;
      sh[b][jl] = f2bf(h0keep);      // xcat0 half0 = h0(t)
      sh[b][8 + jl] = f2bf(hn);      // xcat0 half1 = h1(t)
      outbf[(t * 32 + b) * 512 + j] = f2bf(hn);
    }
    __syncthreads();
    if (w == 0) {
      unsigned long long v0 = *(const unsigned long long*)&sh[bb][hh * 8];
      unsigned long long v1 = *(const unsigned long long*)&sh[bb][hh * 8 + 4];
      unsigned long long* dst = (unsigned long long*)(xcat0 + bb * 1024 + hh * 512 + wg * 8);
      __hip_atomic_store(dst,     v0, __ATOMIC_RELAXED, __HIP_MEMORY_SCOPE_AGENT);
      __hip_atomic_store(dst + 1, v1, __ATOMIC_RELAXED, __HIP_MEMORY_SCOPE_AGENT);
      asm volatile("s_waitcnt vmcnt(0)" ::: "memory");
      if (tid == 0)
        __hip_atomic_store(&flagB[wg], (unsigned int)(t + 1), __ATOMIC_RELAXED, __HIP_MEMORY_SCOPE_AGENT);
    }
  }

  // final state outputs
  float* hT = outs + 131072000;
  float* cT = outs + 131072000 + 32768;
  float* oT = outs + 131072000 + 65536;
  hT[b * 512 + j] = h0keep;
  hT[16384 + b * 512 + j] = h1keep;
  cT[b * 512 + j] = c0r;
  cT[16384 + b * 512 + j] = c1r;
  oT[b * 512 + j] = h1keep;
}

// ---------------------------------------------------------------------------
// per-row online logsumexp + in-place subtract (rows of 32000)
// ---------------------------------------------------------------------------
__global__ __launch_bounds__(256, 1) void lse_fix(float* __restrict__ sc)
{
  const long row = blockIdx.x;
  float* p = sc + row * 32000L;
  const int tid = threadIdx.x;
  float m = -3.0e38f, s = 0.0f;
  for (int i = tid; i < 32000; i += 256) {
    float v = p[i];
    float mn = fmaxf(m, v);
    s = s * __expf(m - mn) + __expf(v - mn);
    m = mn;
  }
#pragma unroll
  for (int off = 32; off > 0; off >>= 1) {
    float mo = __shfl_down(m, off);
    float so = __shfl_down(s, off);
    float mn = fmaxf(m, mo);
    s = s * __expf(m - mn) + so * __expf(mo - mn);
    m = mn;
  }
  __shared__ float lm[4], ls[4], lse_sh;
  if ((tid & 63) == 0) { lm[tid >> 6] = m; ls[tid >> 6] = s; }
  __syncthreads();
  if (tid == 0) {
    float M = lm[0], S = ls[0];
#pragma unroll
    for (int i = 1; i < 4; ++i) {
      float mn = fmaxf(M, lm[i]);
      S = S * __expf(M - mn) + ls[i] * __expf(lm[i] - mn);
      M = mn;
    }
    lse_sh = M + __logf(S);
  }
  __syncthreads();
  const float lse = lse_sh;
  for (int i = tid; i < 32000; i += 256) p[i] -= lse;
}

// ---------------------------------------------------------------------------
extern "C" void kernel_launch(void* const* d_in, const int* in_sizes, int n_in,
                              void* d_out, int out_size, void* d_ws, size_t ws_size,
                              hipStream_t stream) {
  const int*   ids  = (const int*)d_in[0];
  const float* cd   = (const float*)d_in[1];
  const float* wemb = (const float*)d_in[2];
  const float* semb = (const float*)d_in[3];
  const float* h0   = (const float*)d_in[4];
  const float* c0   = (const float*)d_in[5];
  const float* pout = (const float*)d_in[6];
  const float* Wih0 = (const float*)d_in[7];
  const float* Whh0 = (const float*)d_in[8];
  const float* bih0 = (const float*)d_in[9];
  const float* bhh0 = (const float*)d_in[10];
  const float* Wih1 = (const float*)d_in[11];
  const float* Whh1 = (const float*)d_in[12];
  const float* bih1 = (const float*)d_in[13];
  const float* bhh1 = (const float*)d_in[14];
  const float* Wg   = (const float*)d_in[15];
  const float* bg   = (const float*)d_in[16];
  float* out = (float*)d_out;

  char* ws = (char*)d_ws;
  unsigned short* WgBf   = (unsigned short*)(ws);
  unsigned short* W0e    = (unsigned short*)(ws + 32768000);
  unsigned short* Wr0p   = (unsigned short*)(ws + 34865152);
  unsigned short* Wr1p   = (unsigned short*)(ws + 39059456);
  float*          b1p    = (float*)(ws + 43253760);
  float*          bias0c = (float*)(ws + 43261952);
  float*          wcd    = (float*)(ws + 43270144);
  unsigned short* xcat0  = (unsigned short*)(ws + 43278336);
  unsigned short* xcat1  = (unsigned short*)(ws + 43343872);
  unsigned short* embbf  = (unsigned short*)(ws + 43409408);
  unsigned short* outbf  = (unsigned short*)(ws + 47603712);
  float*          P0t    = (float*)(ws + 51798016);
  unsigned int*   flagA  = (unsigned int*)(ws + 85352448);
  unsigned int*   flagB  = (unsigned int*)(ws + 85352448 + 256);

  hipMemsetAsync((void*)flagA, 0, 512, stream);

  prep_k<<<8192, 256, 0, stream>>>(Wg, Wih0, Whh0, Wih1, Whh1,
                                   bih0, bhh0, bih1, bhh1, h0, pout,
                                   WgBf, W0e, Wr0p, Wr1p, b1p, bias0c, wcd, xcat0);

  emb_k<<<4096, 256, 0, stream>>>(ids, wemb, semb, embbf);

  // P0t[perm(g)][tb] = W0e @ emb^T + bias0 + cd*wcd   (M=2048, N=4096)
  gemm_bt<0><<<512, 256, 0, stream>>>(W0e, embbf, 4096, P0t, bias0c, wcd, cd);

  lstm_seq<<<64, 256, 0, stream>>>(Wr0p, Wr1p, P0t, b1p, h0, c0,
                                   xcat0, xcat1, outbf, out, flagA, flagB);

  // logits[tb][v] = out_all @ Wg^T + bg   (M=4096, N=32000) -> d_out scores
  gemm_bt<1><<<8000, 256, 0, stream>>>(outbf, WgBf, 32000, out, bg, nullptr, nullptr);

  lse_fix<<<4096, 256, 0, stream>>>(out);
}

// Round 4
// 1996.629 us; speedup vs baseline: 2.3938x; 1.3531x over previous
//
#include <hip/hip_runtime.h>
#include <hip/hip_bf16.h>

// RNNDecoder: emb -> 2-layer LSTM (seq over T=128) -> generator + log_softmax
// T=128 B=32 E=512 H=512 G=2048 V=32000
//
// R4 changes (exchange structure of lstm_seq):
//  - state buffers A0[2], F[2], H1[2] in [wg][b][8j] layout: each WG writes a
//    contiguous, exclusively-owned 512B block (4 lines) -> no partial-line
//    sharing across WGs (was 8 WGs per line -> serialized RMW at coherence pt,
//    4.4x write amplification, on the critical path).
//  - flags: one per 128B line, uncontended single-writer; all waves poll
//    lane-per-flag with __all.
//  - stale/fresh split: stale half staged + its 16 MFMA K-steps run BEFORE the
//    poll; post-flag path = 32KB stage + 16 MFMA + gates + 512B store.
//  - lse_fix vectorized to float4.
//
// ws layout (bytes):
//  [0)            Wg_bf16   [32000][512]            32,768,000
//  [32768000)     W0e_bf16  [2048][512]              2,097,152
//  [34865152)     Wr0p_bf16 [2048][1024]             4,194,304
//  [39059456)     Wr1p_bf16 [2048][1024]             4,194,304
//  [43253760)     b1p f32   [2048]                       8,192
//  [43261952)     bias0c f32[2048]                       8,192
//  [43270144)     wcd f32   [2048]                       8,192
//  [43409408)     emb_bf16  [4096][512]              4,194,304
//  [47603712)     out_bf16  [4096][512]              4,194,304
//  [51798016)     P0t f32   [2048][4096]            33,554,432
//  [85352448)     flagA u32[64*32]                       8,192
//  [85360640)     flagB u32[64*32]                       8,192
//  [85368832)     A0 bf16 [2][64][32][8]                65,536
//  [85434368)     F  bf16 [2][64][32][8]                65,536
//  [85499904)     H1 bf16 [2][64][32][8]                65,536
// total ~85.6 MB

typedef __attribute__((ext_vector_type(8))) short bf16x8;
typedef __attribute__((ext_vector_type(4))) float f32x4;
typedef __attribute__((ext_vector_type(2))) unsigned long long u64x2;

#define AS1 __attribute__((address_space(1)))
#define AS3 __attribute__((address_space(3)))

__device__ __forceinline__ unsigned short f2bf(float f) {
  unsigned int u = __builtin_bit_cast(unsigned int, f);
  u += 0x7fffu + ((u >> 16) & 1u);            // round-to-nearest-even
  return (unsigned short)(u >> 16);
}

__device__ __forceinline__ void gl16(const void* g, void* l) {
  __builtin_amdgcn_global_load_lds((const AS1 unsigned int*)g,
                                   (AS3 unsigned int*)l, 16, 0, 0);
}

__device__ __forceinline__ float sigm(float x) { return 1.0f / (1.0f + __expf(-x)); }

// ---------------------------------------------------------------------------
// prep: dtype conversion + weight re-layout + initial state buffers
// ---------------------------------------------------------------------------
__global__ __launch_bounds__(256, 1) void prep_k(
    const float* __restrict__ Wg,  const float* __restrict__ Wih0,
    const float* __restrict__ Whh0,const float* __restrict__ Wih1,
    const float* __restrict__ Whh1,const float* __restrict__ bih0,
    const float* __restrict__ bhh0,const float* __restrict__ bih1,
    const float* __restrict__ bhh1,const float* __restrict__ h0,
    const float* __restrict__ pout,
    unsigned short* __restrict__ WgBf, unsigned short* __restrict__ W0e,
    unsigned short* __restrict__ Wr0p, unsigned short* __restrict__ Wr1p,
    float* __restrict__ b1p, float* __restrict__ bias0c,
    float* __restrict__ wcd, unsigned short* __restrict__ A0p,
    unsigned short* __restrict__ Fp, unsigned short* __restrict__ H1p)
{
  const long N0 = 16384000L;           // WgBf
  const long N1 = N0 + 1048576L;       // W0e
  const long N2 = N1 + 2097152L;       // Wr0p
  const long N3 = N2 + 2097152L;       // Wr1p
  const long N4 = N3 + 2048L;          // b1p
  const long N5 = N4 + 2048L;          // bias0c
  const long N6 = N5 + 2048L;          // wcd
  const long N7 = N6 + 49152L;         // state inits (3 x 16384)
  for (long i = blockIdx.x * 256L + threadIdx.x; i < N7; i += 256L * gridDim.x) {
    if (i < N0) {
      WgBf[i] = f2bf(Wg[i]);
    } else if (i < N1) {
      long k = i - N0; int g = (int)(k >> 9); int kk = (int)(k & 511);
      W0e[k] = f2bf(Wih0[g * 1025 + kk]);
    } else if (i < N2) {
      long k = i - N1; int gp = (int)(k >> 10); int kk = (int)(k & 1023);
      int j = gp >> 2, gate = gp & 3; int g = gate * 512 + j;
      float v = (kk < 512) ? Whh0[g * 512 + kk] : Wih0[g * 1025 + 513 + (kk - 512)];
      Wr0p[k] = f2bf(v);
    } else if (i < N3) {
      long k = i - N2; int gp = (int)(k >> 10); int kk = (int)(k & 1023);
      int j = gp >> 2, gate = gp & 3; int g = gate * 512 + j;
      float v = (kk < 512) ? Wih1[g * 512 + kk] : Whh1[g * 512 + (kk - 512)];
      Wr1p[k] = f2bf(v);
    } else if (i < N4) {
      int gp = (int)(i - N3); int j = gp >> 2, gate = gp & 3; int g = gate * 512 + j;
      b1p[gp] = bih1[g] + bhh1[g];
    } else if (i < N5) {
      int g = (int)(i - N4); bias0c[g] = bih0[g] + bhh0[g];
    } else if (i < N6) {
      int g = (int)(i - N5); wcd[g] = Wih0[g * 1025 + 512];
    } else {
      long k = i - N6;                 // 0..49151
      int sub = (int)(k >> 14);        // 0=A0, 1=F, 2=H1
      int e = (int)(k & 16383);
      int b = e >> 9, j = e & 511;
      int off = 16384 + (j >> 3) * 256 + b * 8 + (j & 7);  // parity-1 half
      float v = (sub == 0) ? h0[b * 512 + j]
              : (sub == 1) ? pout[b * 512 + j]
                           : h0[16384 + b * 512 + j];
      unsigned short* dst = (sub == 0) ? A0p : (sub == 1) ? Fp : H1p;
      dst[off] = f2bf(v);
    }
  }
}

// ---------------------------------------------------------------------------
// embedding
// ---------------------------------------------------------------------------
__global__ __launch_bounds__(256, 1) void emb_k(
    const int* __restrict__ ids, const float* __restrict__ wemb,
    const float* __restrict__ semb, unsigned short* __restrict__ ebf)
{
  const int tb = blockIdx.x;
  const int id = ids[tb];
  const int sp = (id < 3) ? (id + 1) : 0;
  const float* wr = wemb + (long)id * 512;
  const float* sr = semb + sp * 512;
  for (int i = threadIdx.x; i < 512; i += 256)
    ebf[tb * 512 + i] = f2bf(wr[i] + sr[i]);
}

// ---------------------------------------------------------------------------
// GEMM: D[m][n] = sum_k A[m][k]*B[n][k]  (A [M][512] bf16, B [N][512] bf16)
// ---------------------------------------------------------------------------
template<int EPI>
__global__ __launch_bounds__(256, 1) void gemm_bt(
    const unsigned short* __restrict__ A,
    const unsigned short* __restrict__ B, int N,
    float* __restrict__ C,
    const float* __restrict__ e0, const float* __restrict__ e1,
    const float* __restrict__ e2)
{
  __shared__ unsigned short sA[4096];
  __shared__ unsigned short sB[4096];
  const int tid = threadIdx.x;
  const int l = tid & 63, w = tid >> 6;
  const int nb = N >> 7;
  const int bid = blockIdx.x;
  const int bm = bid / nb, bn = bid - bm * nb;

  const int u0 = w * 128 + l;
  const int u1 = u0 + 64;
  const int r0 = u0 >> 2, c0 = (u0 & 3) ^ (r0 & 3);
  const int r1 = u1 >> 2, c1 = (u1 & 3) ^ (r1 & 3);
  const unsigned short* ga0 = A + (long)(bm * 128 + r0) * 512 + c0 * 8;
  const unsigned short* ga1 = A + (long)(bm * 128 + r1) * 512 + c1 * 8;
  const unsigned short* gb0 = B + (long)(bn * 128 + r0) * 512 + c0 * 8;
  const unsigned short* gb1 = B + (long)(bn * 128 + r1) * 512 + c1 * 8;
  unsigned short* la0 = sA + (w * 2 + 0) * 512;
  unsigned short* la1 = sA + (w * 2 + 1) * 512;
  unsigned short* lb0 = sB + (w * 2 + 0) * 512;
  unsigned short* lb1 = sB + (w * 2 + 1) * 512;

  const int fr = l & 15, fc = l >> 4;
  const int wm = w >> 1, wn = w & 1;
  int aoff[4], boff[4];
#pragma unroll
  for (int mi = 0; mi < 4; ++mi) {
    int row = wm * 64 + mi * 16 + fr;
    aoff[mi] = row * 64 + ((fc ^ (row & 3)) * 16);
  }
#pragma unroll
  for (int ni = 0; ni < 4; ++ni) {
    int row = wn * 64 + ni * 16 + fr;
    boff[ni] = row * 64 + ((fc ^ (row & 3)) * 16);
  }

  f32x4 acc[4][4];
#pragma unroll
  for (int i = 0; i < 4; ++i)
#pragma unroll
    for (int jq = 0; jq < 4; ++jq) acc[i][jq] = (f32x4){0.f, 0.f, 0.f, 0.f};

  for (int kt = 0; kt < 16; ++kt) {
    __syncthreads();
    gl16(ga0 + kt * 32, la0);
    gl16(ga1 + kt * 32, la1);
    gl16(gb0 + kt * 32, lb0);
    gl16(gb1 + kt * 32, lb1);
    asm volatile("s_waitcnt vmcnt(0)" ::: "memory");
    __syncthreads();
    bf16x8 av[4], bv[4];
#pragma unroll
    for (int mi = 0; mi < 4; ++mi)
      av[mi] = *(const bf16x8*)((const char*)sA + aoff[mi]);
#pragma unroll
    for (int ni = 0; ni < 4; ++ni)
      bv[ni] = *(const bf16x8*)((const char*)sB + boff[ni]);
#pragma unroll
    for (int mi = 0; mi < 4; ++mi)
#pragma unroll
      for (int ni = 0; ni < 4; ++ni)
        acc[mi][ni] = __builtin_amdgcn_mfma_f32_16x16x32_bf16(av[mi], bv[ni], acc[mi][ni], 0, 0, 0);
  }

  const int mbase = bm * 128 + wm * 64;
  const int nbase = bn * 128 + wn * 64;
#pragma unroll
  for (int mi = 0; mi < 4; ++mi)
#pragma unroll
    for (int ni = 0; ni < 4; ++ni) {
      const int col = nbase + ni * 16 + fr;
#pragma unroll
      for (int r = 0; r < 4; ++r) {
        const int row = mbase + mi * 16 + fc * 4 + r;
        float v = acc[mi][ni][r];
        if (EPI == 0) {
          const int gp = ((row & 511) << 2) | (row >> 9);
          v += e0[row] + e2[col] * e1[row];
          C[(long)gp * N + col] = v;
        } else {
          v += e0[col];
          C[(long)row * N + col] = v;
        }
      }
    }
}

// ---------------------------------------------------------------------------
// Persistent sequential LSTM. 64 WGs x 256 thr. WG owns j in [wg*8, wg*8+8).
// State buffers A0/F/H1: [2 parity][64 wg][32 b][8 j] bf16, 512B/WG exclusive.
// Per phase: stage stale half + its MFMAs pre-poll; poll per-line flags;
// stage fresh 32KB; 16 MFMA; gates; 512B store; vmcnt drain; flag store.
// ---------------------------------------------------------------------------
__global__ __launch_bounds__(256, 1) void lstm_seq(
    const unsigned short* __restrict__ Wr0p,
    const unsigned short* __restrict__ Wr1p,
    const float* __restrict__ P0t, const float* __restrict__ b1p,
    const float* __restrict__ h0in, const float* __restrict__ c0in,
    unsigned short* __restrict__ A0p, unsigned short* __restrict__ Fp,
    unsigned short* __restrict__ H1p,
    unsigned short* __restrict__ outbf, float* __restrict__ outs,
    unsigned int* __restrict__ flagA, unsigned int* __restrict__ flagB)
{
  const int tid = threadIdx.x;
  const int wg = blockIdx.x;            // 64
  const int l = tid & 63, w = tid >> 6;
  const int mi = w & 1, ni = w >> 1;
  const int fr = l & 15, fc = l >> 4;

  __shared__ unsigned short sx[32768];  // 64KB staged x, XOR-swizzled
  __shared__ float sg[32][33];
  __shared__ unsigned short sh[32][8];

  const int b = tid & 31, jl = tid >> 5; // jl 0..7
  const int j = wg * 8 + jl;

  float c0r = c0in[b * 512 + j];
  float c1r = c0in[16384 + b * 512 + j];
  float h0keep = 0.0f, h1keep = 0.0f;

  float b1v0 = b1p[j * 4 + 0], b1v1 = b1p[j * 4 + 1];
  float b1v2 = b1p[j * 4 + 2], b1v3 = b1p[j * 4 + 3];

  // MFMA fragment addressing
  const int xrow = mi * 16 + fr;                    // b-row for A frag
  const char* sxb = (const char*)sx + xrow * 2048;
  const int xr = (xrow & 7) << 4;                   // swizzle XOR (bits 4..6)
  const int brow = (wg * 32 + ni * 16 + fr) * 1024 + fc * 8;  // weight row

  // staging constants: chunk u = i*256+tid -> linear 16B at src + u*16B,
  // LDS row (tid&31), col bytes half*1024 + (i*8 + tid>>5)*16, swizzled.
  const int srow = tid & 31;
  const int swz = (srow & 7) << 4;
  char* const sxw = (char*)sx + srow * 2048;
  const int wgj0 = tid >> 5;

#define STAGE(srcp, half)                                                     \
  do {                                                                        \
    unsigned long long q0[8], q1[8];                                          \
    _Pragma("unroll")                                                         \
    for (int i = 0; i < 8; ++i) {                                             \
      int u = i * 256 + tid;                                                  \
      q0[i] = __hip_atomic_load((const unsigned long long*)(srcp) + u * 2,    \
                                __ATOMIC_RELAXED, __HIP_MEMORY_SCOPE_AGENT);  \
      q1[i] = __hip_atomic_load((const unsigned long long*)(srcp) + u * 2 + 1,\
                                __ATOMIC_RELAXED, __HIP_MEMORY_SCOPE_AGENT);  \
    }                                                                         \
    _Pragma("unroll")                                                         \
    for (int i = 0; i < 8; ++i) {                                             \
      int cb = (half) * 1024 + (i * 8 + wgj0) * 16;                           \
      u64x2 v; v.x = q0[i]; v.y = q1[i];                                      \
      *(u64x2*)(sxw + (cb ^ swz)) = v;                                        \
    }                                                                         \
  } while (0)

#define MFMA_HALF(Wp, k0, accv)                                               \
  do {                                                                        \
    _Pragma("unroll")                                                         \
    for (int kt = (k0); kt < (k0) + 16; ++kt) {                               \
      bf16x8 av = *(const bf16x8*)(sxb + ((kt * 64 + fc * 16) ^ xr));         \
      bf16x8 bv = *(const bf16x8*)((Wp) + brow + kt * 32);                    \
      accv = __builtin_amdgcn_mfma_f32_16x16x32_bf16(av, bv, accv, 0, 0, 0);  \
    }                                                                         \
  } while (0)

  for (int t = 0; t < 128; ++t) {
    const int pw = t & 1;          // parity being written this step
    const int pr = (t + 1) & 1;    // parity of t-1 state

    // ================= phase A: layer 0 =================
    float p0a = P0t[(j * 4 + 0) * 4096 + t * 32 + b];
    float p0b = P0t[(j * 4 + 1) * 4096 + t * 32 + b];
    float p0c = P0t[(j * 4 + 2) * 4096 + t * 32 + b];
    float p0d = P0t[(j * 4 + 3) * 4096 + t * 32 + b];

    f32x4 accA = (f32x4){0.f, 0.f, 0.f, 0.f};
    STAGE(A0p + pr * 16384, 0);    // stale: h0(t-1), cols 0-511 (Whh0)
    __syncthreads();
    MFMA_HALF(Wr0p, 0, accA);

    {                              // poll: phase B of t-1 done everywhere
      for (;;) {
        unsigned int f = __hip_atomic_load(&flagB[l << 5], __ATOMIC_RELAXED, __HIP_MEMORY_SCOPE_AGENT);
        if (__all((int)(f >= (unsigned int)t))) break;
        __builtin_amdgcn_s_sleep(1);
      }
      asm volatile("" ::: "memory");
    }
    STAGE(Fp + pr * 16384, 1);     // fresh: out(t-1), cols 512-1023
    __syncthreads();
    MFMA_HALF(Wr0p, 16, accA);
#pragma unroll
    for (int r = 0; r < 4; ++r) sg[mi * 16 + fc * 4 + r][ni * 16 + fr] = accA[r];
    __syncthreads();
    {
      float gi = sg[b][jl * 4 + 0] + p0a;
      float gf = sg[b][jl * 4 + 1] + p0b;
      float gg = sg[b][jl * 4 + 2] + p0c;
      float go = sg[b][jl * 4 + 3] + p0d;
      float cn = sigm(gf) * c0r + sigm(gi) * tanhf(gg);
      float hn = sigm(go) * tanhf(cn);
      c0r = cn; h0keep = hn;
      sh[b][jl] = f2bf(hn);
    }
    __syncthreads();
    if (w == 0) {
      if (l < 32) {
        u64x2 v = *(const u64x2*)&sh[l][0];
        unsigned long long* dst = (unsigned long long*)(A0p + pw * 16384 + wg * 256 + l * 8);
        __hip_atomic_store(dst,     v.x, __ATOMIC_RELAXED, __HIP_MEMORY_SCOPE_AGENT);
        __hip_atomic_store(dst + 1, v.y, __ATOMIC_RELAXED, __HIP_MEMORY_SCOPE_AGENT);
      }
      asm volatile("s_waitcnt vmcnt(0)" ::: "memory");
      if (tid == 0)
        __hip_atomic_store(&flagA[wg << 5], (unsigned int)(t + 1), __ATOMIC_RELAXED, __HIP_MEMORY_SCOPE_AGENT);
    }

    // ================= phase B: layer 1 =================
    f32x4 accB = (f32x4){0.f, 0.f, 0.f, 0.f};
    STAGE(H1p + pr * 16384, 1);    // stale: h1(t-1), cols 512-1023 (Whh1)
    __syncthreads();
    MFMA_HALF(Wr1p, 16, accB);

    {                              // poll: phase A of t done everywhere
      for (;;) {
        unsigned int f = __hip_atomic_load(&flagA[l << 5], __ATOMIC_RELAXED, __HIP_MEMORY_SCOPE_AGENT);
        if (__all((int)(f >= (unsigned int)(t + 1)))) break;
        __builtin_amdgcn_s_sleep(1);
      }
      asm volatile("" ::: "memory");
    }
    STAGE(A0p + pw * 16384, 0);    // fresh: h0(t), cols 0-511 (Wih1)
    __syncthreads();
    MFMA_HALF(Wr1p, 0, accB);
#pragma unroll
    for (int r = 0; r < 4; ++r) sg[mi * 16 + fc * 4 + r][ni * 16 + fr] = accB[r];
    __syncthreads();
    {
      float gi = sg[b][jl * 4 + 0] + b1v0;
      float gf = sg[b][jl * 4 + 1] + b1v1;
      float gg = sg[b][jl * 4 + 2] + b1v2;
      float go = sg[b][jl * 4 + 3] + b1v3;
      float cn = sigm(gf) * c1r + sigm(gi) * tanhf(gg);
      float hn = sigm(go) * tanhf(cn);
      c1r = cn; h1keep = hn;
      sh[b][jl] = f2bf(hn);
      outbf[(t * 32 + b) * 512 + j] = f2bf(hn);
    }
    __syncthreads();
    if (w == 0) {
      const int bb = l & 31;
      unsigned short* base = (l < 32) ? (Fp + pw * 16384) : (H1p + pw * 16384);
      u64x2 v = *(const u64x2*)&sh[bb][0];
      unsigned long long* dst = (unsigned long long*)(base + wg * 256 + bb * 8);
      __hip_atomic_store(dst,     v.x, __ATOMIC_RELAXED, __HIP_MEMORY_SCOPE_AGENT);
      __hip_atomic_store(dst + 1, v.y, __ATOMIC_RELAXED, __HIP_MEMORY_SCOPE_AGENT);
      asm volatile("s_waitcnt vmcnt(0)" ::: "memory");
      if (tid == 0)
        __hip_atomic_store(&flagB[wg << 5], (unsigned int)(t + 1), __ATOMIC_RELAXED, __HIP_MEMORY_SCOPE_AGENT);
    }
  }
#undef STAGE
#undef MFMA_HALF

  // final state outputs
  float* hT = outs + 131072000;
  float* cT = outs + 131072000 + 32768;
  float* oT = outs + 131072000 + 65536;
  hT[b * 512 + j] = h0keep;
  hT[16384 + b * 512 + j] = h1keep;
  cT[b * 512 + j] = c0r;
  cT[16384 + b * 512 + j] = c1r;
  oT[b * 512 + j] = h1keep;
}

// ---------------------------------------------------------------------------
// per-row online logsumexp + in-place subtract (rows of 32000), float4
// ---------------------------------------------------------------------------
__global__ __launch_bounds__(256, 1) void lse_fix(float* __restrict__ sc)
{
  const long row = blockIdx.x;
  float4* p4 = (float4*)(sc + row * 32000L);
  const int tid = threadIdx.x;
  float m = -3.0e38f, s = 0.0f;
  for (int i = tid; i < 8000; i += 256) {
    float4 v = p4[i];
    float m4 = fmaxf(fmaxf(v.x, v.y), fmaxf(v.z, v.w));
    float mn = fmaxf(m, m4);
    s = s * __expf(m - mn) + __expf(v.x - mn) + __expf(v.y - mn)
        + __expf(v.z - mn) + __expf(v.w - mn);
    m = mn;
  }
#pragma unroll
  for (int off = 32; off > 0; off >>= 1) {
    float mo = __shfl_down(m, off);
    float so = __shfl_down(s, off);
    float mn = fmaxf(m, mo);
    s = s * __expf(m - mn) + so * __expf(mo - mn);
    m = mn;
  }
  __shared__ float lm[4], ls[4], lse_sh;
  if ((tid & 63) == 0) { lm[tid >> 6] = m; ls[tid >> 6] = s; }
  __syncthreads();
  if (tid == 0) {
    float M = lm[0], S = ls[0];
#pragma unroll
    for (int i = 1; i < 4; ++i) {
      float mn = fmaxf(M, lm[i]);
      S = S * __expf(M - mn) + ls[i] * __expf(lm[i] - mn);
      M = mn;
    }
    lse_sh = M + __logf(S);
  }
  __syncthreads();
  const float lse = lse_sh;
  for (int i = tid; i < 8000; i += 256) {
    float4 v = p4[i];
    v.x -= lse; v.y -= lse; v.z -= lse; v.w -= lse;
    p4[i] = v;
  }
}

// ---------------------------------------------------------------------------
extern "C" void kernel_launch(void* const* d_in, const int* in_sizes, int n_in,
                              void* d_out, int out_size, void* d_ws, size_t ws_size,
                              hipStream_t stream) {
  const int*   ids  = (const int*)d_in[0];
  const float* cd   = (const float*)d_in[1];
  const float* wemb = (const float*)d_in[2];
  const float* semb = (const float*)d_in[3];
  const float* h0   = (const float*)d_in[4];
  const float* c0   = (const float*)d_in[5];
  const float* pout = (const float*)d_in[6];
  const float* Wih0 = (const float*)d_in[7];
  const float* Whh0 = (const float*)d_in[8];
  const float* bih0 = (const float*)d_in[9];
  const float* bhh0 = (const float*)d_in[10];
  const float* Wih1 = (const float*)d_in[11];
  const float* Whh1 = (const float*)d_in[12];
  const float* bih1 = (const float*)d_in[13];
  const float* bhh1 = (const float*)d_in[14];
  const float* Wg   = (const float*)d_in[15];
  const float* bg   = (const float*)d_in[16];
  float* out = (float*)d_out;

  char* ws = (char*)d_ws;
  unsigned short* WgBf   = (unsigned short*)(ws);
  unsigned short* W0e    = (unsigned short*)(ws + 32768000);
  unsigned short* Wr0p   = (unsigned short*)(ws + 34865152);
  unsigned short* Wr1p   = (unsigned short*)(ws + 39059456);
  float*          b1p    = (float*)(ws + 43253760);
  float*          bias0c = (float*)(ws + 43261952);
  float*          wcd    = (float*)(ws + 43270144);
  unsigned short* embbf  = (unsigned short*)(ws + 43409408);
  unsigned short* outbf  = (unsigned short*)(ws + 47603712);
  float*          P0t    = (float*)(ws + 51798016);
  unsigned int*   flagA  = (unsigned int*)(ws + 85352448);
  unsigned int*   flagB  = (unsigned int*)(ws + 85360640);
  unsigned short* A0p    = (unsigned short*)(ws + 85368832);
  unsigned short* Fp     = (unsigned short*)(ws + 85434368);
  unsigned short* H1p    = (unsigned short*)(ws + 85499904);

  hipMemsetAsync((void*)flagA, 0, 16384, stream);

  prep_k<<<8192, 256, 0, stream>>>(Wg, Wih0, Whh0, Wih1, Whh1,
                                   bih0, bhh0, bih1, bhh1, h0, pout,
                                   WgBf, W0e, Wr0p, Wr1p, b1p, bias0c, wcd,
                                   A0p, Fp, H1p);

  emb_k<<<4096, 256, 0, stream>>>(ids, wemb, semb, embbf);

  // P0t[perm(g)][tb] = W0e @ emb^T + bias0 + cd*wcd   (M=2048, N=4096)
  gemm_bt<0><<<512, 256, 0, stream>>>(W0e, embbf, 4096, P0t, bias0c, wcd, cd);

  lstm_seq<<<64, 256, 0, stream>>>(Wr0p, Wr1p, P0t, b1p, h0, c0,
                                   A0p, Fp, H1p, outbf, out, flagA, flagB);

  // logits[tb][v] = out_all @ Wg^T + bg   (M=4096, N=32000) -> d_out scores
  gemm_bt<1><<<8000, 256, 0, stream>>>(outbf, WgBf, 32000, out, bg, nullptr, nullptr);

  lse_fix<<<4096, 256, 0, stream>>>(out);
}

// Round 5
// 1956.320 us; speedup vs baseline: 2.4431x; 1.0206x over previous
//
#include <hip/hip_runtime.h>
#include <hip/hip_bf16.h>

// RNNDecoder: emb -> 2-layer LSTM (seq over T=128) -> generator + log_softmax
// T=128 B=32 E=512 H=512 G=2048 V=32000
//
// R5 changes (lstm_seq):
//  - Exploit out(t-1) == h1(t-1): single h0 / h1 exchange buffers; LDS sx
//    persists across phases so each phase stages only its FRESH 32KB half.
//    Stale-half MFMA starts immediately at phase entry (no staging pre-poll).
//  - 32 WGs (64 gate rows each) instead of 64: halves straggler set, flag
//    lines, and duplicated stage traffic.
//  - t=0 via read-only init buffers (FOUT=prev_output, H1I=h1(-1)) and an
//    init epoch on flagB (flagB: 1=init staged, t+2=phase B(t) done).
//
// ws layout (bytes):
//  [0)            Wg_bf16   [32000][512]            32,768,000
//  [32768000)     W0e_bf16  [2048][512]              2,097,152
//  [34865152)     Wr0p_bf16 [2048][1024]             4,194,304
//  [39059456)     Wr1p_bf16 [2048][1024]             4,194,304
//  [43253760)     b1p f32   [2048]                       8,192
//  [43261952)     bias0c f32[2048]                       8,192
//  [43270144)     wcd f32   [2048]                       8,192
//  [43409408)     emb_bf16  [4096][512]              4,194,304
//  [47603712)     out_bf16  [4096][512]              4,194,304
//  [51798016)     P0t f32   [2048][4096]            33,554,432
//  [85352448)     flagA u32[32*32]                       4,096
//  [85356544)     flagB u32[32*32]                       4,096
//  [85360640)     H0X  bf16 [32wg][32b][16j]            32,768
//  [85393408)     H1X  bf16 [32wg][32b][16j]            32,768
//  [85426176)     FOUT bf16 [32wg][32b][16j]            32,768
//  [85458944)     H1I  bf16 [32wg][32b][16j]            32,768
// total ~85.5 MB

typedef __attribute__((ext_vector_type(8))) short bf16x8;
typedef __attribute__((ext_vector_type(4))) float f32x4;
typedef __attribute__((ext_vector_type(2))) unsigned long long u64x2;

#define AS1 __attribute__((address_space(1)))
#define AS3 __attribute__((address_space(3)))

__device__ __forceinline__ unsigned short f2bf(float f) {
  unsigned int u = __builtin_bit_cast(unsigned int, f);
  u += 0x7fffu + ((u >> 16) & 1u);            // round-to-nearest-even
  return (unsigned short)(u >> 16);
}

__device__ __forceinline__ void gl16(const void* g, void* l) {
  __builtin_amdgcn_global_load_lds((const AS1 unsigned int*)g,
                                   (AS3 unsigned int*)l, 16, 0, 0);
}

__device__ __forceinline__ float sigm(float x) { return 1.0f / (1.0f + __expf(-x)); }

// ---------------------------------------------------------------------------
// prep: dtype conversion + weight re-layout + initial state buffers
// ---------------------------------------------------------------------------
__global__ __launch_bounds__(256, 1) void prep_k(
    const float* __restrict__ Wg,  const float* __restrict__ Wih0,
    const float* __restrict__ Whh0,const float* __restrict__ Wih1,
    const float* __restrict__ Whh1,const float* __restrict__ bih0,
    const float* __restrict__ bhh0,const float* __restrict__ bih1,
    const float* __restrict__ bhh1,const float* __restrict__ h0,
    const float* __restrict__ pout,
    unsigned short* __restrict__ WgBf, unsigned short* __restrict__ W0e,
    unsigned short* __restrict__ Wr0p, unsigned short* __restrict__ Wr1p,
    float* __restrict__ b1p, float* __restrict__ bias0c,
    float* __restrict__ wcd, unsigned short* __restrict__ H0X,
    unsigned short* __restrict__ FOUT, unsigned short* __restrict__ H1I)
{
  const long N0 = 16384000L;           // WgBf
  const long N1 = N0 + 1048576L;       // W0e
  const long N2 = N1 + 2097152L;       // Wr0p
  const long N3 = N2 + 2097152L;       // Wr1p
  const long N4 = N3 + 2048L;          // b1p
  const long N5 = N4 + 2048L;          // bias0c
  const long N6 = N5 + 2048L;          // wcd
  const long N7 = N6 + 49152L;         // state inits (3 x 16384)
  for (long i = blockIdx.x * 256L + threadIdx.x; i < N7; i += 256L * gridDim.x) {
    if (i < N0) {
      WgBf[i] = f2bf(Wg[i]);
    } else if (i < N1) {
      long k = i - N0; int g = (int)(k >> 9); int kk = (int)(k & 511);
      W0e[k] = f2bf(Wih0[g * 1025 + kk]);
    } else if (i < N2) {
      long k = i - N1; int gp = (int)(k >> 10); int kk = (int)(k & 1023);
      int j = gp >> 2, gate = gp & 3; int g = gate * 512 + j;
      float v = (kk < 512) ? Whh0[g * 512 + kk] : Wih0[g * 1025 + 513 + (kk - 512)];
      Wr0p[k] = f2bf(v);
    } else if (i < N3) {
      long k = i - N2; int gp = (int)(k >> 10); int kk = (int)(k & 1023);
      int j = gp >> 2, gate = gp & 3; int g = gate * 512 + j;
      float v = (kk < 512) ? Wih1[g * 512 + kk] : Whh1[g * 512 + (kk - 512)];
      Wr1p[k] = f2bf(v);
    } else if (i < N4) {
      int gp = (int)(i - N3); int j = gp >> 2, gate = gp & 3; int g = gate * 512 + j;
      b1p[gp] = bih1[g] + bhh1[g];
    } else if (i < N5) {
      int g = (int)(i - N4); bias0c[g] = bih0[g] + bhh0[g];
    } else if (i < N6) {
      int g = (int)(i - N5); wcd[g] = Wih0[g * 1025 + 512];
    } else {
      long k = i - N6;                 // 0..49151
      int sub = (int)(k >> 14);        // 0=H0X(h0 l0), 1=H1I(h0 l1), 2=FOUT(pout)
      int e = (int)(k & 16383);
      int wgx = e >> 9, b = (e >> 4) & 31, jl = e & 15;
      int j = wgx * 16 + jl;
      float v = (sub == 0) ? h0[b * 512 + j]
              : (sub == 1) ? h0[16384 + b * 512 + j]
                           : pout[b * 512 + j];
      unsigned short* dst = (sub == 0) ? H0X : (sub == 1) ? H1I : FOUT;
      dst[e] = f2bf(v);
    }
  }
}

// ---------------------------------------------------------------------------
// embedding
// ---------------------------------------------------------------------------
__global__ __launch_bounds__(256, 1) void emb_k(
    const int* __restrict__ ids, const float* __restrict__ wemb,
    const float* __restrict__ semb, unsigned short* __restrict__ ebf)
{
  const int tb = blockIdx.x;
  const int id = ids[tb];
  const int sp = (id < 3) ? (id + 1) : 0;
  const float* wr = wemb + (long)id * 512;
  const float* sr = semb + sp * 512;
  for (int i = threadIdx.x; i < 512; i += 256)
    ebf[tb * 512 + i] = f2bf(wr[i] + sr[i]);
}

// ---------------------------------------------------------------------------
// GEMM: D[m][n] = sum_k A[m][k]*B[n][k]  (A [M][512] bf16, B [N][512] bf16)
// ---------------------------------------------------------------------------
template<int EPI>
__global__ __launch_bounds__(256, 1) void gemm_bt(
    const unsigned short* __restrict__ A,
    const unsigned short* __restrict__ B, int N,
    float* __restrict__ C,
    const float* __restrict__ e0, const float* __restrict__ e1,
    const float* __restrict__ e2)
{
  __shared__ unsigned short sA[4096];
  __shared__ unsigned short sB[4096];
  const int tid = threadIdx.x;
  const int l = tid & 63, w = tid >> 6;
  const int nb = N >> 7;
  const int bid = blockIdx.x;
  const int bm = bid / nb, bn = bid - bm * nb;

  const int u0 = w * 128 + l;
  const int u1 = u0 + 64;
  const int r0 = u0 >> 2, c0 = (u0 & 3) ^ (r0 & 3);
  const int r1 = u1 >> 2, c1 = (u1 & 3) ^ (r1 & 3);
  const unsigned short* ga0 = A + (long)(bm * 128 + r0) * 512 + c0 * 8;
  const unsigned short* ga1 = A + (long)(bm * 128 + r1) * 512 + c1 * 8;
  const unsigned short* gb0 = B + (long)(bn * 128 + r0) * 512 + c0 * 8;
  const unsigned short* gb1 = B + (long)(bn * 128 + r1) * 512 + c1 * 8;
  unsigned short* la0 = sA + (w * 2 + 0) * 512;
  unsigned short* la1 = sA + (w * 2 + 1) * 512;
  unsigned short* lb0 = sB + (w * 2 + 0) * 512;
  unsigned short* lb1 = sB + (w * 2 + 1) * 512;

  const int fr = l & 15, fc = l >> 4;
  const int wm = w >> 1, wn = w & 1;
  int aoff[4], boff[4];
#pragma unroll
  for (int mi = 0; mi < 4; ++mi) {
    int row = wm * 64 + mi * 16 + fr;
    aoff[mi] = row * 64 + ((fc ^ (row & 3)) * 16);
  }
#pragma unroll
  for (int ni = 0; ni < 4; ++ni) {
    int row = wn * 64 + ni * 16 + fr;
    boff[ni] = row * 64 + ((fc ^ (row & 3)) * 16);
  }

  f32x4 acc[4][4];
#pragma unroll
  for (int i = 0; i < 4; ++i)
#pragma unroll
    for (int jq = 0; jq < 4; ++jq) acc[i][jq] = (f32x4){0.f, 0.f, 0.f, 0.f};

  for (int kt = 0; kt < 16; ++kt) {
    __syncthreads();
    gl16(ga0 + kt * 32, la0);
    gl16(ga1 + kt * 32, la1);
    gl16(gb0 + kt * 32, lb0);
    gl16(gb1 + kt * 32, lb1);
    asm volatile("s_waitcnt vmcnt(0)" ::: "memory");
    __syncthreads();
    bf16x8 av[4], bv[4];
#pragma unroll
    for (int mi = 0; mi < 4; ++mi)
      av[mi] = *(const bf16x8*)((const char*)sA + aoff[mi]);
#pragma unroll
    for (int ni = 0; ni < 4; ++ni)
      bv[ni] = *(const bf16x8*)((const char*)sB + boff[ni]);
#pragma unroll
    for (int mi = 0; mi < 4; ++mi)
#pragma unroll
      for (int ni = 0; ni < 4; ++ni)
        acc[mi][ni] = __builtin_amdgcn_mfma_f32_16x16x32_bf16(av[mi], bv[ni], acc[mi][ni], 0, 0, 0);
  }

  const int mbase = bm * 128 + wm * 64;
  const int nbase = bn * 128 + wn * 64;
#pragma unroll
  for (int mi = 0; mi < 4; ++mi)
#pragma unroll
    for (int ni = 0; ni < 4; ++ni) {
      const int col = nbase + ni * 16 + fr;
#pragma unroll
      for (int r = 0; r < 4; ++r) {
        const int row = mbase + mi * 16 + fc * 4 + r;
        float v = acc[mi][ni][r];
        if (EPI == 0) {
          const int gp = ((row & 511) << 2) | (row >> 9);
          v += e0[row] + e2[col] * e1[row];
          C[(long)gp * N + col] = v;
        } else {
          v += e0[col];
          C[(long)row * N + col] = v;
        }
      }
    }
}

// ---------------------------------------------------------------------------
// Persistent sequential LSTM. 32 WGs x 256 thr. WG owns gp rows
// [wg*64, wg*64+64) i.e. j in [wg*16, wg*16+16).
// sx LDS [32 b][1024 cols] persists: cols 0-511 = h0, cols 512-1023 = h1.
// Per phase: pre-poll MFMA on resident half; poll; stage fresh 32KB half;
// MFMA; gates; 1KB exclusive store; drain; flag.
// flagA: t+1 = phase A(t) done. flagB: 1 = init staged, t+2 = B(t) done.
// ---------------------------------------------------------------------------
__global__ __launch_bounds__(256, 1) void lstm_seq(
    const unsigned short* __restrict__ Wr0p,
    const unsigned short* __restrict__ Wr1p,
    const float* __restrict__ P0t, const float* __restrict__ b1p,
    const float* __restrict__ c0in,
    unsigned short* __restrict__ H0X, unsigned short* __restrict__ H1X,
    const unsigned short* __restrict__ FOUT, const unsigned short* __restrict__ H1I,
    unsigned short* __restrict__ outbf, float* __restrict__ outs,
    unsigned int* __restrict__ flagA, unsigned int* __restrict__ flagB)
{
  const int tid = threadIdx.x;
  const int wg = blockIdx.x;            // 32
  const int l = tid & 63, w = tid >> 6;
  const int fr = l & 15, fc = l >> 4;

  __shared__ unsigned short sx[32768];  // 64KB: [32 b][1024 cols], swizzled
  __shared__ float sg[32][65];
  __shared__ unsigned short sh[32][16];

  const int b = tid & 31, jl0 = tid >> 5;       // jl0 0..7; thread owns jl0, jl0+8
  const int sb = l >> 1, sjh = l & 1;           // stage/store lane mapping

  float c0r[2], c1r[2], h0k[2], h1k[2];
#pragma unroll
  for (int jq = 0; jq < 2; ++jq) {
    c0r[jq] = c0in[b * 512 + wg * 16 + jl0 + jq * 8];
    c1r[jq] = c0in[16384 + b * 512 + wg * 16 + jl0 + jq * 8];
    h0k[jq] = 0.f; h1k[jq] = 0.f;
  }

  float b1v[8];
#pragma unroll
  for (int jq = 0; jq < 2; ++jq)
#pragma unroll
    for (int g = 0; g < 4; ++g)
      b1v[jq * 4 + g] = b1p[(wg * 16 + jl0 + jq * 8) * 4 + g];

  // MFMA addressing
  const char* sxb0 = (const char*)sx + fr * 2048;          // b-rows 0-15
  const char* sxb1 = (const char*)sx + (16 + fr) * 2048;   // b-rows 16-31
  const int xr = (fr & 7) << 4;
  const int wrow = (wg * 64 + w * 16 + fr) * 1024 + fc * 8;

  // staging LDS base
  char* const sxw = (char*)sx + sb * 2048;
  const int sswz = (sb & 7) << 4;

#define STAGE2(srcp, half)                                                    \
  do {                                                                        \
    unsigned long long q0[8], q1[8];                                          \
    _Pragma("unroll")                                                         \
    for (int i = 0; i < 8; ++i) {                                             \
      int u = i * 256 + tid;                                                  \
      q0[i] = __hip_atomic_load((const unsigned long long*)(srcp) + u * 2,    \
                                __ATOMIC_RELAXED, __HIP_MEMORY_SCOPE_AGENT);  \
      q1[i] = __hip_atomic_load((const unsigned long long*)(srcp) + u * 2 + 1,\
                                __ATOMIC_RELAXED, __HIP_MEMORY_SCOPE_AGENT);  \
    }                                                                         \
    _Pragma("unroll")                                                         \
    for (int i = 0; i < 8; ++i) {                                             \
      int cb = (half) * 1024 + (i * 4 + w) * 32 + sjh * 16;                   \
      u64x2 v; v.x = q0[i]; v.y = q1[i];                                      \
      *(u64x2*)(sxw + (cb ^ sswz)) = v;                                       \
    }                                                                         \
  } while (0)

#define MFMA_HALF(Wp, k0, a0v, a1v)                                           \
  do {                                                                        \
    _Pragma("unroll")                                                         \
    for (int kt = (k0); kt < (k0) + 16; ++kt) {                               \
      bf16x8 bv = *(const bf16x8*)((Wp) + wrow + kt * 32);                    \
      bf16x8 x0 = *(const bf16x8*)(sxb0 + ((kt * 64 + fc * 16) ^ xr));        \
      bf16x8 x1 = *(const bf16x8*)(sxb1 + ((kt * 64 + fc * 16) ^ xr));        \
      a0v = __builtin_amdgcn_mfma_f32_16x16x32_bf16(x0, bv, a0v, 0, 0, 0);    \
      a1v = __builtin_amdgcn_mfma_f32_16x16x32_bf16(x1, bv, a1v, 0, 0, 0);    \
    }                                                                         \
  } while (0)

#define POLL(flags, tgt)                                                      \
  do {                                                                        \
    const unsigned int* fp = (flags) + ((l & 31) << 5);                       \
    for (;;) {                                                                \
      unsigned int f = __hip_atomic_load(fp, __ATOMIC_RELAXED,                \
                                         __HIP_MEMORY_SCOPE_AGENT);           \
      if (__all((int)(f >= (unsigned int)(tgt)))) break;                      \
      __builtin_amdgcn_s_sleep(1);                                            \
    }                                                                         \
    asm volatile("" ::: "memory");                                            \
  } while (0)

  // ---- pre-loop: stage h0 init into cols 0-511, signal init epoch ----
  STAGE2(H0X, 0);
  __syncthreads();
  if (tid == 0)
    __hip_atomic_store(&flagB[wg << 5], 1u, __ATOMIC_RELAXED, __HIP_MEMORY_SCOPE_AGENT);

  for (int t = 0; t < 128; ++t) {
    // ================= phase A: layer 0 =================
    float p0v[8];
#pragma unroll
    for (int jq = 0; jq < 2; ++jq)
#pragma unroll
      for (int g = 0; g < 4; ++g)
        p0v[jq * 4 + g] =
            P0t[(long)((wg * 16 + jl0 + jq * 8) * 4 + g) * 4096 + t * 32 + b];

    f32x4 accA0 = (f32x4){0.f, 0.f, 0.f, 0.f};
    f32x4 accA1 = (f32x4){0.f, 0.f, 0.f, 0.f};
    MFMA_HALF(Wr0p, 0, accA0, accA1);      // resident h0(t-1), cols 0-511

    POLL(flagB, t + 1);                    // h1(t-1) ready everywhere (or init)
    if (t == 0) STAGE2(FOUT, 1); else STAGE2(H1X, 1);
    __syncthreads();
    MFMA_HALF(Wr0p, 16, accA0, accA1);     // fresh h1(t-1)/out, cols 512-1023
#pragma unroll
    for (int r = 0; r < 4; ++r) {
      sg[fc * 4 + r][w * 16 + fr] = accA0[r];
      sg[16 + fc * 4 + r][w * 16 + fr] = accA1[r];
    }
    __syncthreads();
#pragma unroll
    for (int jq = 0; jq < 2; ++jq) {
      const int jl = jl0 + jq * 8;
      float gi = sg[b][jl * 4 + 0] + p0v[jq * 4 + 0];
      float gf = sg[b][jl * 4 + 1] + p0v[jq * 4 + 1];
      float gg = sg[b][jl * 4 + 2] + p0v[jq * 4 + 2];
      float go = sg[b][jl * 4 + 3] + p0v[jq * 4 + 3];
      float cn = sigm(gf) * c0r[jq] + sigm(gi) * tanhf(gg);
      float hn = sigm(go) * tanhf(cn);
      c0r[jq] = cn; h0k[jq] = hn;
      sh[b][jl] = f2bf(hn);
    }
    __syncthreads();
    if (w == 0) {
      u64x2 v = *(const u64x2*)&sh[sb][sjh * 8];
      unsigned long long* dst =
          (unsigned long long*)(H0X + wg * 512 + sb * 16 + sjh * 8);
      __hip_atomic_store(dst,     v.x, __ATOMIC_RELAXED, __HIP_MEMORY_SCOPE_AGENT);
      __hip_atomic_store(dst + 1, v.y, __ATOMIC_RELAXED, __HIP_MEMORY_SCOPE_AGENT);
      asm volatile("s_waitcnt vmcnt(0)" ::: "memory");
      if (tid == 0)
        __hip_atomic_store(&flagA[wg << 5], (unsigned int)(t + 1),
                           __ATOMIC_RELAXED, __HIP_MEMORY_SCOPE_AGENT);
    }

    // ================= phase B: layer 1 =================
    f32x4 accB0 = (f32x4){0.f, 0.f, 0.f, 0.f};
    f32x4 accB1 = (f32x4){0.f, 0.f, 0.f, 0.f};
    if (t == 0) {                          // cols 512-1023 hold FOUT; need h1(-1)
      STAGE2(H1I, 1);
      __syncthreads();
    }
    MFMA_HALF(Wr1p, 16, accB0, accB1);     // resident h1(t-1), cols 512-1023

    POLL(flagA, t + 1);                    // h0(t) ready everywhere
    STAGE2(H0X, 0);
    __syncthreads();
    MFMA_HALF(Wr1p, 0, accB0, accB1);      // fresh h0(t), cols 0-511
#pragma unroll
    for (int r = 0; r < 4; ++r) {
      sg[fc * 4 + r][w * 16 + fr] = accB0[r];
      sg[16 + fc * 4 + r][w * 16 + fr] = accB1[r];
    }
    __syncthreads();
#pragma unroll
    for (int jq = 0; jq < 2; ++jq) {
      const int jl = jl0 + jq * 8;
      float gi = sg[b][jl * 4 + 0] + b1v[jq * 4 + 0];
      float gf = sg[b][jl * 4 + 1] + b1v[jq * 4 + 1];
      float gg = sg[b][jl * 4 + 2] + b1v[jq * 4 + 2];
      float go = sg[b][jl * 4 + 3] + b1v[jq * 4 + 3];
      float cn = sigm(gf) * c1r[jq] + sigm(gi) * tanhf(gg);
      float hn = sigm(go) * tanhf(cn);
      c1r[jq] = cn; h1k[jq] = hn;
      sh[b][jl] = f2bf(hn);
    }
    __syncthreads();
    if (w == 0) {
      u64x2 v = *(const u64x2*)&sh[sb][sjh * 8];
      unsigned long long* dst =
          (unsigned long long*)(H1X + wg * 512 + sb * 16 + sjh * 8);
      __hip_atomic_store(dst,     v.x, __ATOMIC_RELAXED, __HIP_MEMORY_SCOPE_AGENT);
      __hip_atomic_store(dst + 1, v.y, __ATOMIC_RELAXED, __HIP_MEMORY_SCOPE_AGENT);
      asm volatile("s_waitcnt vmcnt(0)" ::: "memory");
      if (tid == 0)
        __hip_atomic_store(&flagB[wg << 5], (unsigned int)(t + 2),
                           __ATOMIC_RELAXED, __HIP_MEMORY_SCOPE_AGENT);
    } else if (w == 1) {
      u64x2 v = *(const u64x2*)&sh[sb][sjh * 8];
      *(u64x2*)(outbf + (t * 32 + sb) * 512 + wg * 16 + sjh * 8) = v;
    }
  }
#undef STAGE2
#undef MFMA_HALF
#undef POLL

  // final state outputs
  float* hT = outs + 131072000;
  float* cT = outs + 131072000 + 32768;
  float* oT = outs + 131072000 + 65536;
#pragma unroll
  for (int jq = 0; jq < 2; ++jq) {
    const int j = wg * 16 + jl0 + jq * 8;
    hT[b * 512 + j] = h0k[jq];
    hT[16384 + b * 512 + j] = h1k[jq];
    cT[b * 512 + j] = c0r[jq];
    cT[16384 + b * 512 + j] = c1r[jq];
    oT[b * 512 + j] = h1k[jq];
  }
}

// ---------------------------------------------------------------------------
// per-row online logsumexp + in-place subtract (rows of 32000), float4
// ---------------------------------------------------------------------------
__global__ __launch_bounds__(256, 1) void lse_fix(float* __restrict__ sc)
{
  const long row = blockIdx.x;
  float4* p4 = (float4*)(sc + row * 32000L);
  const int tid = threadIdx.x;
  float m = -3.0e38f, s = 0.0f;
  for (int i = tid; i < 8000; i += 256) {
    float4 v = p4[i];
    float m4 = fmaxf(fmaxf(v.x, v.y), fmaxf(v.z, v.w));
    float mn = fmaxf(m, m4);
    s = s * __expf(m - mn) + __expf(v.x - mn) + __expf(v.y - mn)
        + __expf(v.z - mn) + __expf(v.w - mn);
    m = mn;
  }
#pragma unroll
  for (int off = 32; off > 0; off >>= 1) {
    float mo = __shfl_down(m, off);
    float so = __shfl_down(s, off);
    float mn = fmaxf(m, mo);
    s = s * __expf(m - mn) + so * __expf(mo - mn);
    m = mn;
  }
  __shared__ float lm[4], ls[4], lse_sh;
  if ((tid & 63) == 0) { lm[tid >> 6] = m; ls[tid >> 6] = s; }
  __syncthreads();
  if (tid == 0) {
    float M = lm[0], S = ls[0];
#pragma unroll
    for (int i = 1; i < 4; ++i) {
      float mn = fmaxf(M, lm[i]);
      S = S * __expf(M - mn) + ls[i] * __expf(lm[i] - mn);
      M = mn;
    }
    lse_sh = M + __logf(S);
  }
  __syncthreads();
  const float lse = lse_sh;
  for (int i = tid; i < 8000; i += 256) {
    float4 v = p4[i];
    v.x -= lse; v.y -= lse; v.z -= lse; v.w -= lse;
    p4[i] = v;
  }
}

// ---------------------------------------------------------------------------
extern "C" void kernel_launch(void* const* d_in, const int* in_sizes, int n_in,
                              void* d_out, int out_size, void* d_ws, size_t ws_size,
                              hipStream_t stream) {
  const int*   ids  = (const int*)d_in[0];
  const float* cd   = (const float*)d_in[1];
  const float* wemb = (const float*)d_in[2];
  const float* semb = (const float*)d_in[3];
  const float* h0   = (const float*)d_in[4];
  const float* c0   = (const float*)d_in[5];
  const float* pout = (const float*)d_in[6];
  const float* Wih0 = (const float*)d_in[7];
  const float* Whh0 = (const float*)d_in[8];
  const float* bih0 = (const float*)d_in[9];
  const float* bhh0 = (const float*)d_in[10];
  const float* Wih1 = (const float*)d_in[11];
  const float* Whh1 = (const float*)d_in[12];
  const float* bih1 = (const float*)d_in[13];
  const float* bhh1 = (const float*)d_in[14];
  const float* Wg   = (const float*)d_in[15];
  const float* bg   = (const float*)d_in[16];
  float* out = (float*)d_out;

  char* ws = (char*)d_ws;
  unsigned short* WgBf   = (unsigned short*)(ws);
  unsigned short* W0e    = (unsigned short*)(ws + 32768000);
  unsigned short* Wr0p   = (unsigned short*)(ws + 34865152);
  unsigned short* Wr1p   = (unsigned short*)(ws + 39059456);
  float*          b1p    = (float*)(ws + 43253760);
  float*          bias0c = (float*)(ws + 43261952);
  float*          wcd    = (float*)(ws + 43270144);
  unsigned short* embbf  = (unsigned short*)(ws + 43409408);
  unsigned short* outbf  = (unsigned short*)(ws + 47603712);
  float*          P0t    = (float*)(ws + 51798016);
  unsigned int*   flagA  = (unsigned int*)(ws + 85352448);
  unsigned int*   flagB  = (unsigned int*)(ws + 85356544);
  unsigned short* H0X    = (unsigned short*)(ws + 85360640);
  unsigned short* H1X    = (unsigned short*)(ws + 85393408);
  unsigned short* FOUT   = (unsigned short*)(ws + 85426176);
  unsigned short* H1I    = (unsigned short*)(ws + 85458944);

  hipMemsetAsync((void*)flagA, 0, 8192, stream);

  prep_k<<<8192, 256, 0, stream>>>(Wg, Wih0, Whh0, Wih1, Whh1,
                                   bih0, bhh0, bih1, bhh1, h0, pout,
                                   WgBf, W0e, Wr0p, Wr1p, b1p, bias0c, wcd,
                                   H0X, FOUT, H1I);

  emb_k<<<4096, 256, 0, stream>>>(ids, wemb, semb, embbf);

  // P0t[perm(g)][tb] = W0e @ emb^T + bias0 + cd*wcd   (M=2048, N=4096)
  gemm_bt<0><<<512, 256, 0, stream>>>(W0e, embbf, 4096, P0t, bias0c, wcd, cd);

  lstm_seq<<<32, 256, 0, stream>>>(Wr0p, Wr1p, P0t, b1p, c0,
                                   H0X, H1X, FOUT, H1I, outbf, out, flagA, flagB);

  // logits[tb][v] = out_all @ Wg^T + bg   (M=4096, N=32000) -> d_out scores
  gemm_bt<1><<<8000, 256, 0, stream>>>(outbf, WgBf, 32000, out, bg, nullptr, nullptr);

  lse_fix<<<4096, 256, 0, stream>>>(out);
}